// Round 19
// baseline (1034.972 us; speedup 1.0000x reference)
//
#include <hip/hip_runtime.h>
#include <hip/hip_bf16.h>
#include <cstdint>

#define B_ 2
#define S_ 2048
#define H_ 2048
#define NH_ 16
#define QL_ 1536
#define KVL_ 512
#define NOPE_ 128
#define ROPE_ 64
#define QHD_ 192
#define VHD_ 128
#define FF_ 8192
#define BS_ (B_ * S_)            // 4096 rows
#define CKVP_ 640                // padded ckv width (576 -> 640 for N%128==0)
#define KVW_ (NOPE_ + VHD_)      // 256 per head

typedef __hip_bfloat16 bf16;
typedef __attribute__((ext_vector_type(8))) short short8_t;  // 8 bf16 (4 VGPRs)
typedef __attribute__((ext_vector_type(4))) float f32x4;

__device__ __forceinline__ float ldf(const float* p, size_t i) { return p[i]; }
__device__ __forceinline__ float ldf(const bf16* p, size_t i) { return __bfloat162float(p[i]); }
__device__ __forceinline__ void stf(float* p, size_t i, float v) { p[i] = v; }
__device__ __forceinline__ void stf(bf16* p, size_t i, float v) { p[i] = __float2bfloat16(v); }

__device__ __forceinline__ unsigned short bf16bits(float x)
{
    union { bf16 h; unsigned short u; } c;
    c.h = __float2bfloat16(x);
    return c.u;
}

// vectorized 4-wide load/store helpers (G13)
__device__ __forceinline__ float4 ld4(const float* p, int i)
{
    return ((const float4*)p)[i];
}
__device__ __forceinline__ float4 ld4(const bf16* p, int i)
{
    ushort4 u = *(const ushort4*)((const unsigned short*)p + i * 4);
    float4 v;
    v.x = __uint_as_float((unsigned)u.x << 16);
    v.y = __uint_as_float((unsigned)u.y << 16);
    v.z = __uint_as_float((unsigned)u.z << 16);
    v.w = __uint_as_float((unsigned)u.w << 16);
    return v;
}
__device__ __forceinline__ void st4(float* p, int i, float4 v)
{
    ((float4*)p)[i] = v;
}
__device__ __forceinline__ void st4(bf16* p, int i, float4 v)
{
    ushort4 u;
    u.x = bf16bits(v.x); u.y = bf16bits(v.y);
    u.z = bf16bits(v.z); u.w = bf16bits(v.w);
    *(ushort4*)((unsigned short*)p + i * 4) = u;
}

__device__ __forceinline__ void gload16(const void* g, void* l)
{
    __builtin_amdgcn_global_load_lds((const unsigned int*)g, (unsigned int*)l, 16, 0, 0);
}

// ---------------------------------------------------------------------------
// Transpose + convert v2: in fp32 [K][N] -> out bf16 [Npad][K]. 64(k)x32(n)
// tile; packed 32-bit bf16-pair stores. Rows n>=N zeroed.
// ---------------------------------------------------------------------------
__global__ __launch_bounds__(256) void transp_bf16(
    const float* __restrict__ in, bf16* __restrict__ out, int K, int N, int Npad)
{
    __shared__ float t[64][33];
    const int n0 = blockIdx.x * 32, k0 = blockIdx.y * 64;
    const int tx = threadIdx.x, ty = threadIdx.y;
    for (int r = ty; r < 64; r += 8) {
        const int n = n0 + tx;
        t[r][tx] = (n < N) ? in[(size_t)(k0 + r) * N + n] : 0.f;
    }
    __syncthreads();
    unsigned* outu = (unsigned*)out;
    for (int r = ty; r < 32; r += 8) {
        const unsigned lo = bf16bits(t[2 * tx][r]);
        const unsigned hi = bf16bits(t[2 * tx + 1][r]);
        outu[((size_t)(n0 + r) * K + k0) / 2 + tx] = lo | (hi << 16);
    }
}

// ---------------------------------------------------------------------------
// RMSNorm v2 (vectorized, G13).
// ---------------------------------------------------------------------------
template<typename InT, typename OutT>
__global__ __launch_bounds__(256) void rmsnorm2(
    const InT* __restrict__ in, const float* __restrict__ w,
    OutT* __restrict__ out, int cols, int istride, int ostride)
{
    const int row = blockIdx.x;
    const InT* ip = in + (size_t)row * istride;
    OutT* op = out + (size_t)row * ostride;
    const int c4 = cols >> 2;

    float ss = 0.f;
    for (int c = threadIdx.x; c < c4; c += 256) {
        float4 v = ld4(ip, c);
        ss = fmaf(v.x, v.x, fmaf(v.y, v.y, fmaf(v.z, v.z, fmaf(v.w, v.w, ss))));
    }
    #pragma unroll
    for (int off = 32; off; off >>= 1) ss += __shfl_xor(ss, off);
    __shared__ float red[4];
    if ((threadIdx.x & 63) == 0) red[threadIdx.x >> 6] = ss;
    __syncthreads();
    const float total = red[0] + red[1] + red[2] + red[3];
    const float scale = rsqrtf(total / (float)cols + 1e-6f);
    for (int c = threadIdx.x; c < c4; c += 256) {
        float4 v = ld4(ip, c);
        float4 g = ((const float4*)w)[c];
        float4 o;
        o.x = v.x * scale * g.x;
        o.y = v.y * scale * g.y;
        o.z = v.z * scale * g.z;
        o.w = v.w * scale * g.w;
        st4(op, c, o);
    }
}

// ---------------------------------------------------------------------------
// Epilogue helper shared by the big GEMMs.
// ---------------------------------------------------------------------------
template<int MODE, typename OutT>
__device__ __forceinline__ void epi_store(
    OutT* __restrict__ C, const float* __restrict__ Df, const bf16* __restrict__ Db,
    int N, int row, int col, float v)
{
    const size_t off = (size_t)row * N + col;
    if (MODE == 1) v += Df[off];
    if (MODE == 2) {
        const float g = __bfloat162float(Db[off]);
        v *= g / (1.f + __expf(-g));
    }
    stf(C, off, v);
}

__device__ __forceinline__ short8_t ldsfrag(const short* half_base, int r, int c)
{
    return *(const short8_t*)(half_base + r * 64 + ((c ^ (r & 7)) << 3));
}

// ---------------------------------------------------------------------------
// 256x256 GEMM v2 (R11, proven): spread-stage, 4 phases/tile. MODE 3: kvb
// fused epilogue — d<128 -> Kh bf16 head-major; d>=128 -> fp32 C (v part).
// ---------------------------------------------------------------------------
template<int MODE, typename OutT>
__global__ __launch_bounds__(512, 2) void gemm256(
    const bf16* __restrict__ A, const bf16* __restrict__ BT,
    const float* __restrict__ Df, const bf16* __restrict__ Db,
    OutT* __restrict__ C, bf16* __restrict__ KhO, int M, int N, int K)
{
    __shared__ short lds[2][2][2][128 * 64];   // [buf][A/B][half] = 128 KiB

    const int tid = threadIdx.x;
    const int wid = tid >> 6, lane = tid & 63;
    const int wm = wid >> 2, wn = wid & 3;
    const int l16 = lane & 15, hk = lane >> 4;

    const int nwg = gridDim.x * gridDim.y;
    const int orig = blockIdx.y * gridDim.x + blockIdx.x;
    const int q = nwg >> 3, r8 = nwg & 7;
    const int xcd = orig & 7, lid = orig >> 3;
    const int wg = (xcd < r8 ? xcd * (q + 1) : r8 * (q + 1) + (xcd - r8) * q) + lid;
    const int bn = (wg % gridDim.x) * 256;
    const int bm = (wg / gridDim.x) * 256;

    f32x4 acc[8][4] = {};
    const int nt = K >> 6;

    auto stage_half = [&](const bf16* gbase, short* lbase) {
        #pragma unroll
        for (int i = 0; i < 2; ++i) {
            const int ch = i * 512 + tid;
            const int row = ch >> 3, pc = ch & 7;
            const int gc = pc ^ (row & 7);
            const char* src = (const char*)(gbase + (size_t)row * K + gc * 8);
            char* dst = (char*)lbase + (i * 512 + wid * 64) * 16;
            gload16(src, dst);
        }
    };

    stage_half(A + (size_t)bm * K,          &lds[0][0][0][0]);
    stage_half(A + (size_t)(bm + 128) * K,  &lds[0][0][1][0]);
    stage_half(BT + (size_t)bn * K,         &lds[0][1][0][0]);
    stage_half(BT + (size_t)(bn + 128) * K, &lds[0][1][1][0]);
    asm volatile("s_waitcnt vmcnt(0)" ::: "memory");
    __builtin_amdgcn_s_barrier();

    for (int t = 0; t < nt; ++t) {
        const int c = t & 1;
        const short* Ah = &lds[c][0][wm][0];
        const short* Bh = &lds[c][1][wn >> 1][0];
        const int brr = (wn & 1) * 64;
        const int k1 = (t + 1) << 6;
        const bool pf = (t + 1 < nt);

        short8_t bfr[4][2], afr[2][2];

        #pragma unroll
        for (int ph = 0; ph < 4; ++ph) {
            if (ph == 0) {
                #pragma unroll
                for (int nf = 0; nf < 4; ++nf)
                    #pragma unroll
                    for (int ks = 0; ks < 2; ++ks)
                        bfr[nf][ks] = ldsfrag(Bh, brr + nf * 16 + l16, ks * 4 + hk);
            }
            #pragma unroll
            for (int mi = 0; mi < 2; ++mi)
                #pragma unroll
                for (int ks = 0; ks < 2; ++ks)
                    afr[mi][ks] = ldsfrag(Ah, ph * 32 + mi * 16 + l16, ks * 4 + hk);
            if (pf) {
                if (ph == 0) {
                    stage_half(A + (size_t)bm * K + k1,          &lds[c ^ 1][0][0][0]);
                    stage_half(A + (size_t)(bm + 128) * K + k1,  &lds[c ^ 1][0][1][0]);
                } else if (ph == 1) {
                    stage_half(BT + (size_t)bn * K + k1,         &lds[c ^ 1][1][0][0]);
                    stage_half(BT + (size_t)(bn + 128) * K + k1, &lds[c ^ 1][1][1][0]);
                }
            }
            __builtin_amdgcn_s_setprio(1);
            #pragma unroll
            for (int mi = 0; mi < 2; ++mi)
                #pragma unroll
                for (int nf = 0; nf < 4; ++nf)
                    #pragma unroll
                    for (int ks = 0; ks < 2; ++ks)
                        acc[ph * 2 + mi][nf] = __builtin_amdgcn_mfma_f32_16x16x32_bf16(
                            afr[mi][ks], bfr[nf][ks], acc[ph * 2 + mi][nf], 0, 0, 0);
            __builtin_amdgcn_s_setprio(0);
            if (ph == 3) asm volatile("s_waitcnt vmcnt(0)" ::: "memory");
            __builtin_amdgcn_s_barrier();
        }
    }

    const int r0 = bm + wm * 128 + (lane >> 4) * 4;
    const int c0 = bn + wn * 64 + l16;
    #pragma unroll
    for (int mf = 0; mf < 8; ++mf)
        #pragma unroll
        for (int nf = 0; nf < 4; ++nf)
            #pragma unroll
            for (int r = 0; r < 4; ++r) {
                const int row = r0 + mf * 16 + r;
                const int col = c0 + nf * 16;
                float v = acc[mf][nf][r];
                if (MODE == 3) {
                    const int d = col & 255;
                    if (d < NOPE_) {
                        const int hh = col >> 8;
                        const int bb = row >> 11, s = row & 2047;
                        KhO[((size_t)(bb * NH_ + hh) * S_ + s) * QHD_ + d] = __float2bfloat16(v);
                    } else {
                        C[(size_t)row * N + col] = v;
                    }
                } else {
                    epi_store<MODE>(C, Df, Db, N, row, col, v);
                }
            }
}

// ---------------------------------------------------------------------------
// 256x128 GEMM v4 (R14, proven) — BK=64, single phase/tile.
// ---------------------------------------------------------------------------
template<int MODE, typename OutT>
__global__ __launch_bounds__(512, 2) void gemm256n128(
    const bf16* __restrict__ A, const bf16* __restrict__ BT,
    const float* __restrict__ Df, const bf16* __restrict__ Db,
    OutT* __restrict__ C, int M, int N, int K)
{
    __shared__ short lds[2][3][128 * 64];   // [buf][A0/A1/B] = 96 KiB

    const int tid = threadIdx.x;
    const int wid = tid >> 6, lane = tid & 63;
    const int wm = wid >> 1, wn = wid & 1;
    const int l16 = lane & 15, hk = lane >> 4;

    const int nwg = gridDim.x * gridDim.y;
    const int orig = blockIdx.y * gridDim.x + blockIdx.x;
    const int q = nwg >> 3, r8 = nwg & 7;
    const int xcd = orig & 7, lid = orig >> 3;
    const int wg = (xcd < r8 ? xcd * (q + 1) : r8 * (q + 1) + (xcd - r8) * q) + lid;
    const int bn = (wg % gridDim.x) * 128;
    const int bm = (wg / gridDim.x) * 256;

    f32x4 acc[4][4] = {};
    const int nt = K >> 6;

    auto stage_half = [&](const bf16* gbase, short* lbase) {
        #pragma unroll
        for (int i = 0; i < 2; ++i) {
            const int ch = i * 512 + tid;
            const int row = ch >> 3, pc = ch & 7;
            const int gc = pc ^ (row & 7);
            const char* src = (const char*)(gbase + (size_t)row * K + gc * 8);
            char* dst = (char*)lbase + (i * 512 + wid * 64) * 16;
            gload16(src, dst);
        }
    };

    stage_half(A + (size_t)bm * K,          &lds[0][0][0]);
    stage_half(A + (size_t)(bm + 128) * K,  &lds[0][1][0]);
    stage_half(BT + (size_t)bn * K,         &lds[0][2][0]);
    asm volatile("s_waitcnt vmcnt(0)" ::: "memory");
    __builtin_amdgcn_s_barrier();

    for (int t = 0; t < nt; ++t) {
        const int c = t & 1;
        const short* Ah = &lds[c][wm >> 1][0];
        const short* Bh = &lds[c][2][0];
        const int arr = (wm & 1) * 64;
        const int brr = wn * 64;
        const int k1 = (t + 1) << 6;
        const bool pf = (t + 1 < nt);

        short8_t bfr[4][2], afr[4][2];

        #pragma unroll
        for (int nf = 0; nf < 4; ++nf)
            #pragma unroll
            for (int ks = 0; ks < 2; ++ks)
                bfr[nf][ks] = ldsfrag(Bh, brr + nf * 16 + l16, ks * 4 + hk);
        #pragma unroll
        for (int mi = 0; mi < 4; ++mi)
            #pragma unroll
            for (int ks = 0; ks < 2; ++ks)
                afr[mi][ks] = ldsfrag(Ah, arr + mi * 16 + l16, ks * 4 + hk);
        if (pf) {
            stage_half(A + (size_t)bm * K + k1,         &lds[c ^ 1][0][0]);
            stage_half(A + (size_t)(bm + 128) * K + k1, &lds[c ^ 1][1][0]);
            stage_half(BT + (size_t)bn * K + k1,        &lds[c ^ 1][2][0]);
        }
        __builtin_amdgcn_s_setprio(1);
        #pragma unroll
        for (int mi = 0; mi < 4; ++mi)
            #pragma unroll
            for (int nf = 0; nf < 4; ++nf)
                #pragma unroll
                for (int ks = 0; ks < 2; ++ks)
                    acc[mi][nf] = __builtin_amdgcn_mfma_f32_16x16x32_bf16(
                        afr[mi][ks], bfr[nf][ks], acc[mi][nf], 0, 0, 0);
        __builtin_amdgcn_s_setprio(0);
        asm volatile("s_waitcnt vmcnt(0)" ::: "memory");
        __builtin_amdgcn_s_barrier();
    }

    const int r0 = bm + wm * 64 + (lane >> 4) * 4;
    const int c0 = bn + wn * 64 + l16;
    #pragma unroll
    for (int mf = 0; mf < 4; ++mf)
        #pragma unroll
        for (int nf = 0; nf < 4; ++nf)
            #pragma unroll
            for (int r = 0; r < 4; ++r)
                epi_store<MODE>(C, Df, Db, N, r0 + mf * 16 + r, c0 + nf * 16, acc[mf][nf][r]);
}

// ---------------------------------------------------------------------------
// Fused gate+up GEMM v4 (R14, proven): single phase/tile.
// ---------------------------------------------------------------------------
__global__ __launch_bounds__(512, 2) void gemm256dual(
    const bf16* __restrict__ A, const bf16* __restrict__ BG,
    const bf16* __restrict__ BU, bf16* __restrict__ C, int M, int N, int K)
{
    __shared__ short lds[2][4][128 * 64];   // [buf][A0/A1/BG/BU] = 128 KiB

    const int tid = threadIdx.x;
    const int wid = tid >> 6, lane = tid & 63;
    const int wm = wid >> 1, wn = wid & 1;
    const int l16 = lane & 15, hk = lane >> 4;

    const int nwg = gridDim.x * gridDim.y;
    const int orig = blockIdx.y * gridDim.x + blockIdx.x;
    const int q = nwg >> 3, r8 = nwg & 7;
    const int xcd = orig & 7, lid = orig >> 3;
    const int wg = (xcd < r8 ? xcd * (q + 1) : r8 * (q + 1) + (xcd - r8) * q) + lid;
    const int bm = (wg % gridDim.y) * 256;
    const int bn = (wg / gridDim.y) * 128;

    f32x4 ag[4][4] = {}, au[4][4] = {};
    const int nt = K >> 6;

    auto stage_half = [&](const bf16* gbase, short* lbase) {
        #pragma unroll
        for (int i = 0; i < 2; ++i) {
            const int ch = i * 512 + tid;
            const int row = ch >> 3, pc = ch & 7;
            const int gc = pc ^ (row & 7);
            const char* src = (const char*)(gbase + (size_t)row * K + gc * 8);
            char* dst = (char*)lbase + (i * 512 + wid * 64) * 16;
            gload16(src, dst);
        }
    };

    stage_half(A + (size_t)bm * K,          &lds[0][0][0]);
    stage_half(A + (size_t)(bm + 128) * K,  &lds[0][1][0]);
    stage_half(BG + (size_t)bn * K,         &lds[0][2][0]);
    stage_half(BU + (size_t)bn * K,         &lds[0][3][0]);
    asm volatile("s_waitcnt vmcnt(0)" ::: "memory");
    __builtin_amdgcn_s_barrier();

    for (int t = 0; t < nt; ++t) {
        const int c = t & 1;
        const short* Ah = &lds[c][wm >> 1][0];
        const short* Gs = &lds[c][2][0];
        const short* Us = &lds[c][3][0];
        const int arr = (wm & 1) * 64;
        const int brr = wn * 64;
        const int k1 = (t + 1) << 6;

        short8_t gfr[4][2], ufr[4][2], afr[4][2];

        #pragma unroll
        for (int nf = 0; nf < 4; ++nf)
            #pragma unroll
            for (int ks = 0; ks < 2; ++ks) {
                gfr[nf][ks] = ldsfrag(Gs, brr + nf * 16 + l16, ks * 4 + hk);
                ufr[nf][ks] = ldsfrag(Us, brr + nf * 16 + l16, ks * 4 + hk);
            }
        #pragma unroll
        for (int mi = 0; mi < 4; ++mi)
            #pragma unroll
            for (int ks = 0; ks < 2; ++ks)
                afr[mi][ks] = ldsfrag(Ah, arr + mi * 16 + l16, ks * 4 + hk);
        if (t + 1 < nt) {
            stage_half(A + (size_t)bm * K + k1,         &lds[c ^ 1][0][0]);
            stage_half(A + (size_t)(bm + 128) * K + k1, &lds[c ^ 1][1][0]);
            stage_half(BG + (size_t)bn * K + k1,        &lds[c ^ 1][2][0]);
            stage_half(BU + (size_t)bn * K + k1,        &lds[c ^ 1][3][0]);
        }
        __builtin_amdgcn_s_setprio(1);
        #pragma unroll
        for (int mi = 0; mi < 4; ++mi)
            #pragma unroll
            for (int nf = 0; nf < 4; ++nf)
                #pragma unroll
                for (int ks = 0; ks < 2; ++ks) {
                    ag[mi][nf] = __builtin_amdgcn_mfma_f32_16x16x32_bf16(
                        afr[mi][ks], gfr[nf][ks], ag[mi][nf], 0, 0, 0);
                    au[mi][nf] = __builtin_amdgcn_mfma_f32_16x16x32_bf16(
                        afr[mi][ks], ufr[nf][ks], au[mi][nf], 0, 0, 0);
                }
        __builtin_amdgcn_s_setprio(0);

        asm volatile("s_waitcnt vmcnt(0)" ::: "memory");
        __builtin_amdgcn_s_barrier();
    }

    const int r0 = bm + wm * 64 + (lane >> 4) * 4;
    const int c0 = bn + wn * 64 + l16;
    #pragma unroll
    for (int mf = 0; mf < 4; ++mf)
        #pragma unroll
        for (int nf = 0; nf < 4; ++nf)
            #pragma unroll
            for (int r = 0; r < 4; ++r) {
                const float gg = ag[mf][nf][r];
                const float uu = au[mf][nf][r];
                const float v = gg / (1.f + __expf(-gg)) * uu;
                C[(size_t)(r0 + mf * 16 + r) * N + c0 + nf * 16] = __float2bfloat16(v);
            }
}

// ---------------------------------------------------------------------------
// RoPE v2: q_pe in place; k_pe -> all 16 heads' Kh[...][128:192].
// ---------------------------------------------------------------------------
__global__ __launch_bounds__(256) void rope_kernel(
    bf16* __restrict__ q, const float* __restrict__ ckv,
    bf16* __restrict__ Kh, const int* __restrict__ pos_ids,
    const float* __restrict__ sinT, const float* __restrict__ cosT)
{
    const int wid = blockIdx.x * 4 + (threadIdx.x >> 6);
    const int lane = threadIdx.x & 63;
    const int NQ = BS_ * NH_;

    int bs;
    float x;
    bf16* bptr = nullptr;
    if (wid < NQ) {
        bs = wid >> 4;
        bptr = q + (size_t)wid * QHD_ + NOPE_;
        x = __bfloat162float(bptr[lane]);
    } else {
        bs = wid - NQ;
        x = ckv[(size_t)bs * CKVP_ + KVL_ + lane];
    }
    const int pos = pos_ids[bs];
    const float c  = cosT[pos * ROPE_ + lane];
    const float sn = sinT[pos * ROPE_ + lane];
    const int j = lane & 31;
    const float x0 = __shfl(x, 2 * j);
    const float x1 = __shfl(x, 2 * j + 1);
    const float res = (lane < 32) ? fmaf(x0, c, -x1 * sn) : fmaf(x1, c, x0 * sn);
    if (bptr) {
        bptr[lane] = __float2bfloat16(res);
    } else {
        const int bb = bs >> 11, s = bs & 2047;
        const bf16 rv = __float2bfloat16(res);
        #pragma unroll
        for (int hh = 0; hh < NH_; ++hh)
            Kh[((size_t)(bb * NH_ + hh) * S_ + s) * QHD_ + NOPE_ + lane] = rv;
    }
}

// ---------------------------------------------------------------------------
// pack_vt: Vt (B,NH,128,S) bf16 <- V = KV[...,128:256] fp32, transposed.
// ---------------------------------------------------------------------------
__global__ __launch_bounds__(256) void pack_vt(
    const float* __restrict__ KV, bf16* __restrict__ Vt)
{
    __shared__ float t[32][33];
    const int s0 = blockIdx.x * 32, d0 = blockIdx.y * 32;
    const int bh = blockIdx.z;
    const int tx = threadIdx.x & 31, ty = threadIdx.x >> 5;
    for (int r = ty; r < 32; r += 8)
        t[r][tx] = KV[(((size_t)(bh >> 4) * S_ + s0 + r) * NH_ + (bh & 15)) * KVW_ + NOPE_ + d0 + tx];
    __syncthreads();
    for (int r = ty; r < 32; r += 8)
        Vt[((size_t)bh * VHD_ + d0 + r) * S_ + s0 + tx] = __float2bfloat16(t[tx][r]);
}

// ---------------------------------------------------------------------------
// MFMA flash attention v6 — single-buffer LDS (57 KiB) + launch_bounds
// (512,4): VGPR cap 128 -> target 2 blocks/CU for cross-block stall hiding.
// ---------------------------------------------------------------------------
__global__ __launch_bounds__(512, 4) void attn_mfma(
    const bf16* __restrict__ Qp, const bf16* __restrict__ Kh,
    const bf16* __restrict__ Vt, bf16* __restrict__ outp)
{
    __shared__ __align__(16) short Ks[64][192];
    __shared__ __align__(16) short Vs[128][64];
    __shared__ __align__(16) short Ps[8][16][64];

    const int tid = threadIdx.x;
    const int wid = tid >> 6, lane = tid & 63;
    const int l16 = lane & 15;
    const int hk  = lane >> 4;
    const int lk  = hk << 3;
    const int pr  = hk << 2;
    const int lx  = l16 & 7;

    const int bid = blockIdx.x;
    const int orig = (bid & 7) * 64 + (bid >> 3);
    const int j  = orig & 15;
    const int gh = orig >> 4;
    const int h = gh & 15, b = gh >> 4;

    const int setB = wid >> 2;
    const int qblk = setB ? (31 - j) : j;
    const int qw = qblk * 64 + (wid & 3) * 16;
    const int myNt = qblk + 1;
    const int ntStage = 32 - j;

    short8_t qf[6];
    const bf16* qbase = Qp + (((size_t)b * S_ + qw + l16) * NH_ + h) * QHD_;
    #pragma unroll
    for (int kk = 0; kk < 6; ++kk)
        qf[kk] = *(const short8_t*)(qbase + kk * 32 + lk);

    const bf16* Khb = Kh + (size_t)(b * NH_ + h) * S_ * QHD_;
    const bf16* Vtb = Vt + (size_t)(b * NH_ + h) * VHD_ * S_;

    f32x4 o[8] = {};
    float mr[4] = {-3.0e38f, -3.0e38f, -3.0e38f, -3.0e38f};
    float lr[4] = {0.f, 0.f, 0.f, 0.f};
    const float scale = 0.07216878364870323f;

    const int krow = tid >> 3, kc0 = (tid & 7) * 3;
    const int vrow = tid >> 2, vc0 = (tid & 3) * 2;

    short8_t kreg[3], vreg[2];
    auto load_tile = [&](int kt) {
        const short* ksrc = (const short*)(Khb + ((size_t)(kt * 64 + krow)) * QHD_);
        kreg[0] = *(const short8_t*)(ksrc + (kc0 + 0) * 8);
        kreg[1] = *(const short8_t*)(ksrc + (kc0 + 1) * 8);
        kreg[2] = *(const short8_t*)(ksrc + (kc0 + 2) * 8);
        const short* vsrc = (const short*)(Vtb + (size_t)vrow * S_ + kt * 64);
        vreg[0] = *(const short8_t*)(vsrc + (vc0 + 0) * 8);
        vreg[1] = *(const short8_t*)(vsrc + (vc0 + 1) * 8);
    };
    auto write_tile = [&]() {
        const int kx = krow & 7, vx = vrow & 7;
        *(short8_t*)&Ks[krow][((kc0 + 0) ^ kx) << 3] = kreg[0];
        *(short8_t*)&Ks[krow][((kc0 + 1) ^ kx) << 3] = kreg[1];
        *(short8_t*)&Ks[krow][((kc0 + 2) ^ kx) << 3] = kreg[2];
        *(short8_t*)&Vs[vrow][((vc0 + 0) ^ vx) << 3] = vreg[0];
        *(short8_t*)&Vs[vrow][((vc0 + 1) ^ vx) << 3] = vreg[1];
    };

    load_tile(0);

    for (int t = 0; t < ntStage; ++t) {
        write_tile();
        __syncthreads();
        if (t + 1 < ntStage) load_tile(t + 1);
        if (t < myNt) {
            const int k0 = t << 6;
            f32x4 s[4] = {};
            #pragma unroll
            for (int kk = 0; kk < 6; ++kk) {
                #pragma unroll
                for (int n = 0; n < 4; ++n) {
                    short8_t kf = *(const short8_t*)&Ks[n * 16 + l16][((kk * 4 + hk) ^ lx) << 3];
                    s[n] = __builtin_amdgcn_mfma_f32_16x16x32_bf16(qf[kk], kf, s[n], 0, 0, 0);
                }
            }
            if (t == myNt - 1) {
                #pragma unroll
                for (int n = 0; n < 4; ++n) {
                    const int kg = k0 + n * 16 + l16;
                    #pragma unroll
                    for (int r = 0; r < 4; ++r) {
                        if (kg > qw + pr + r) s[n][r] = -3.0e38f;
                    }
                }
            }
            #pragma unroll
            for (int r = 0; r < 4; ++r) {
                float rm = fmaxf(fmaxf(s[0][r], s[1][r]), fmaxf(s[2][r], s[3][r]));
                rm = fmaxf(rm, __shfl_xor(rm, 1));
                rm = fmaxf(rm, __shfl_xor(rm, 2));
                rm = fmaxf(rm, __shfl_xor(rm, 4));
                rm = fmaxf(rm, __shfl_xor(rm, 8));
                const float mnew = fmaxf(mr[r], rm);
                const float corr = __expf((mr[r] - mnew) * scale);
                mr[r] = mnew;
                float rs = 0.f;
                #pragma unroll
                for (int n = 0; n < 4; ++n) {
                    const float p = __expf((s[n][r] - mnew) * scale);
                    s[n][r] = p;
                    rs += p;
                }
                rs += __shfl_xor(rs, 1);
                rs += __shfl_xor(rs, 2);
                rs += __shfl_xor(rs, 4);
                rs += __shfl_xor(rs, 8);
                lr[r] = lr[r] * corr + rs;
                #pragma unroll
                for (int n = 0; n < 8; ++n) o[n][r] *= corr;
            }
            #pragma unroll
            for (int n = 0; n < 4; ++n) {
                #pragma unroll
                for (int r = 0; r < 4; ++r) {
                    union { bf16 hh; short u; } cv;
                    cv.hh = __float2bfloat16(s[n][r]);
                    const int row = pr + r;
                    const int col = (((n * 2 + (l16 >> 3)) ^ (row & 7)) << 3) + (l16 & 7);
                    Ps[wid][row][col] = cv.u;
                }
            }
            #pragma unroll
            for (int kk2 = 0; kk2 < 2; ++kk2) {
                short8_t pf = *(const short8_t*)&Ps[wid][l16][((kk2 * 4 + hk) ^ lx) << 3];
                #pragma unroll
                for (int n = 0; n < 8; ++n) {
                    short8_t vf = *(const short8_t*)&Vs[n * 16 + l16][((kk2 * 4 + hk) ^ lx) << 3];
                    o[n] = __builtin_amdgcn_mfma_f32_16x16x32_bf16(pf, vf, o[n], 0, 0, 0);
                }
            }
        }
        __syncthreads();
    }

    float inv[4];
    #pragma unroll
    for (int r = 0; r < 4; ++r) inv[r] = 1.f / lr[r];
    bf16* ob = outp + (((size_t)b * S_ + qw + pr) * NH_ + h) * VHD_;
    #pragma unroll
    for (int r = 0; r < 4; ++r)
        #pragma unroll
        for (int n = 0; n < 8; ++n)
            ob[(size_t)r * (NH_ * VHD_) + n * 16 + l16] = __float2bfloat16(o[n][r] * inv[r]);
}

// ---------------------------------------------------------------------------
// Launch
// ---------------------------------------------------------------------------
extern "C" void kernel_launch(void* const* d_in, const int* in_sizes, int n_in,
                              void* d_out, int out_size, void* d_ws, size_t ws_size,
                              hipStream_t stream)
{
    const float* hidden  = (const float*)d_in[0];
    const float* ln1_w   = (const float*)d_in[1];
    const float* q_a_k   = (const float*)d_in[2];
    const float* q_a_ln  = (const float*)d_in[3];
    const float* q_b_k   = (const float*)d_in[4];
    const float* kv_a_k  = (const float*)d_in[5];
    const float* kv_a_ln = (const float*)d_in[6];
    const float* kv_b_k  = (const float*)d_in[7];
    const float* o_k     = (const float*)d_in[8];
    const float* ln2_w   = (const float*)d_in[9];
    const float* gate_k  = (const float*)d_in[10];
    const float* up_k    = (const float*)d_in[11];
    const float* down_k  = (const float*)d_in[12];
    const float* sinT    = (const float*)d_in[13];
    const float* cosT    = (const float*)d_in[14];
    const int*   pos     = (const int*)d_in[15];
    float* out = (float*)d_out;
    char* ws = (char*)d_ws;

    // ---- Phase-1 workspace layout ----
    bf16* qaT   = (bf16*)(ws + 0);            // [1536][2048]  6,291,456
    bf16* qbT   = (bf16*)(ws + 6291456);      // [3072][1536]  9,437,184
    bf16* kvaT  = (bf16*)(ws + 15728640);     // [640][2048]   2,621,440
    bf16* kvbT  = (bf16*)(ws + 18350080);     // [4096][512]   4,194,304
    bf16* oT    = (bf16*)(ws + 22544384);     // [2048][2048]  8,388,608
    bf16* Xb    = (bf16*)(ws + 30932992);     // [4096][2048] 16,777,216
    bf16* QAb   = (bf16*)(ws + 47710208);     // [4096][1536] 12,582,912
    bf16* CKVNb = (bf16*)(ws + 60293120);     // [4096][512]   4,194,304
    bf16* Qb    = (bf16*)(ws + 64487424);     // [4096][3072] 25,165,824
    float* CKV  = (float*)(ws + 89653248);    // [4096][640]  10,485,760
    float* KV   = (float*)(ws + 100139008);   // [4096][4096] 67,108,864
    bf16* ATTNb = (bf16*)(ws + 167247872);    // [4096][2048] 16,777,216
    bf16* Vt    = (bf16*)(ws + 0);            // overlays dead qaT/qbT/kvaT
    bf16* Kh    = (bf16*)(ws + 30932992);     // overlays dead Xb+QAb(part)
    // ---- Phase-2 layout ----
    bf16* gateT = (bf16*)(ws + 0);            // [8192][2048] 33,554,432
    bf16* upT   = (bf16*)(ws + 33554432);     // [8192][2048] 33,554,432
    bf16* downT = (bf16*)(ws + 67108864);     // [2048][8192] 33,554,432
    bf16* X2b   = (bf16*)(ws + 100663296);    // [4096][2048] 16,777,216
    bf16* MLPb  = (bf16*)(ws + 117440512);    // [4096][8192] 67,108,864

    const dim3 tb(32, 8);

    // 0. weight transposes (attention-phase weights); grid (Npad/32, K/64)
    transp_bf16<<<dim3(1536 / 32, 2048 / 64), tb, 0, stream>>>(q_a_k, qaT, 2048, 1536, 1536);
    transp_bf16<<<dim3(3072 / 32, 1536 / 64), tb, 0, stream>>>(q_b_k, qbT, 1536, 3072, 3072);
    transp_bf16<<<dim3(640 / 32, 2048 / 64), tb, 0, stream>>>(kv_a_k, kvaT, 2048, 576, 640);
    transp_bf16<<<dim3(4096 / 32, 512 / 64), tb, 0, stream>>>(kv_b_k, kvbT, 512, 4096, 4096);
    transp_bf16<<<dim3(2048 / 32, 2048 / 64), tb, 0, stream>>>(o_k, oT, 2048, 2048, 2048);

    // 1. Xb = rmsnorm(hidden)
    rmsnorm2<float, bf16><<<BS_, 256, 0, stream>>>(hidden, ln1_w, Xb, H_, H_, H_);
    // 2. QAb = Xb @ qaT   (n128 v4, grid 12x16)
    gemm256n128<0, bf16><<<dim3(QL_ / 128, BS_ / 256), 512, 0, stream>>>(
        Xb, qaT, nullptr, nullptr, QAb, BS_, QL_, H_);
    // 3. QAb = rmsnorm(QAb) in place
    rmsnorm2<bf16, bf16><<<BS_, 256, 0, stream>>>(QAb, q_a_ln, QAb, QL_, QL_, QL_);
    // 4. Qb = QAb @ qbT   (n128 v4, grid 24x16)
    gemm256n128<0, bf16><<<dim3((NH_ * QHD_) / 128, BS_ / 256), 512, 0, stream>>>(
        QAb, qbT, nullptr, nullptr, Qb, BS_, NH_ * QHD_, QL_);
    // 5. CKV = Xb @ kvaT (fp32, padded width 640; n128 v4, grid 5x16)
    gemm256n128<0, float><<<dim3(CKVP_ / 128, BS_ / 256), 512, 0, stream>>>(
        Xb, kvaT, nullptr, nullptr, CKV, BS_, CKVP_, H_);
    // 6. CKVNb = rmsnorm(CKV[:, :512])
    rmsnorm2<float, bf16><<<BS_, 256, 0, stream>>>(CKV, kv_a_ln, CKVNb, KVL_, CKVP_, KVL_);
    // 7. KV/Kh = CKVNb @ kvbT (MODE 3: k_nope -> Kh bf16, v -> KV fp32)
    gemm256<3, float><<<dim3((NH_ * KVW_) / 256, BS_ / 256), 512, 0, stream>>>(
        CKVNb, kvbT, nullptr, nullptr, KV, Kh, BS_, NH_ * KVW_, KVL_);
    // 8. RoPE: q_pe in place; k_pe -> Kh[*][128:192] for all heads
    rope_kernel<<<(BS_ * NH_ + BS_) / 4, 256, 0, stream>>>(Qb, CKV, Kh, pos, sinT, cosT);
    // 9. pack V^T (bf16 transposed)
    pack_vt<<<dim3(S_ / 32, VHD_ / 32, B_ * NH_), 256, 0, stream>>>(KV, Vt);
    // 10. MFMA flash attention v6 -> ATTNb
    attn_mfma<<<dim3(512), 512, 0, stream>>>(Qb, Kh, Vt, ATTNb);
    // 11. d_out = ATTNb @ oT + hidden (fp32, n128 v4, grid 16x16)
    gemm256n128<1, float><<<dim3(H_ / 128, BS_ / 256), 512, 0, stream>>>(
        ATTNb, oT, hidden, nullptr, out, BS_, H_, NH_ * VHD_);

    // 12. MLP-phase weight transposes
    transp_bf16<<<dim3(8192 / 32, 2048 / 64), tb, 0, stream>>>(gate_k, gateT, 2048, 8192, 8192);
    transp_bf16<<<dim3(8192 / 32, 2048 / 64), tb, 0, stream>>>(up_k, upT, 2048, 8192, 8192);
    transp_bf16<<<dim3(2048 / 32, 8192 / 64), tb, 0, stream>>>(down_k, downT, 8192, 2048, 2048);

    // 13. X2b = rmsnorm(d_out)
    rmsnorm2<float, bf16><<<BS_, 256, 0, stream>>>(out, ln2_w, X2b, H_, H_, H_);
    // 14. MLPb = silu(X2b @ gateT) * (X2b @ upT)  — fused dual GEMM (v4)
    gemm256dual<<<dim3(FF_ / 128, BS_ / 256), 512, 0, stream>>>(
        X2b, gateT, upT, MLPb, BS_, FF_, H_);
    // 15. d_out = MLPb @ downT + d_out (n128 v4, grid 16x16)
    gemm256n128<1, float><<<dim3(H_ / 128, BS_ / 256), 512, 0, stream>>>(
        MLPb, downT, out, nullptr, out, BS_, H_, FF_);
}

// Round 20
// 897.846 us; speedup vs baseline: 1.1527x; 1.1527x over previous
//
#include <hip/hip_runtime.h>
#include <hip/hip_bf16.h>
#include <cstdint>

#define B_ 2
#define S_ 2048
#define H_ 2048
#define NH_ 16
#define QL_ 1536
#define KVL_ 512
#define NOPE_ 128
#define ROPE_ 64
#define QHD_ 192
#define VHD_ 128
#define FF_ 8192
#define BS_ (B_ * S_)            // 4096 rows
#define CKVP_ 640                // padded ckv width (576 -> 640 for N%128==0)
#define KVW_ (NOPE_ + VHD_)      // 256 per head

typedef __hip_bfloat16 bf16;
typedef __attribute__((ext_vector_type(8))) short short8_t;  // 8 bf16 (4 VGPRs)
typedef __attribute__((ext_vector_type(4))) float f32x4;

__device__ __forceinline__ float ldf(const float* p, size_t i) { return p[i]; }
__device__ __forceinline__ float ldf(const bf16* p, size_t i) { return __bfloat162float(p[i]); }
__device__ __forceinline__ void stf(float* p, size_t i, float v) { p[i] = v; }
__device__ __forceinline__ void stf(bf16* p, size_t i, float v) { p[i] = __float2bfloat16(v); }

__device__ __forceinline__ unsigned short bf16bits(float x)
{
    union { bf16 h; unsigned short u; } c;
    c.h = __float2bfloat16(x);
    return c.u;
}

// vectorized 4-wide load/store helpers (G13)
__device__ __forceinline__ float4 ld4(const float* p, int i)
{
    return ((const float4*)p)[i];
}
__device__ __forceinline__ float4 ld4(const bf16* p, int i)
{
    ushort4 u = *(const ushort4*)((const unsigned short*)p + i * 4);
    float4 v;
    v.x = __uint_as_float((unsigned)u.x << 16);
    v.y = __uint_as_float((unsigned)u.y << 16);
    v.z = __uint_as_float((unsigned)u.z << 16);
    v.w = __uint_as_float((unsigned)u.w << 16);
    return v;
}
__device__ __forceinline__ void st4(float* p, int i, float4 v)
{
    ((float4*)p)[i] = v;
}
__device__ __forceinline__ void st4(bf16* p, int i, float4 v)
{
    ushort4 u;
    u.x = bf16bits(v.x); u.y = bf16bits(v.y);
    u.z = bf16bits(v.z); u.w = bf16bits(v.w);
    *(ushort4*)((unsigned short*)p + i * 4) = u;
}

__device__ __forceinline__ void gload16(const void* g, void* l)
{
    __builtin_amdgcn_global_load_lds((const unsigned int*)g, (unsigned int*)l, 16, 0, 0);
}

// ---------------------------------------------------------------------------
// Transpose + convert v2: in fp32 [K][N] -> out bf16 [Npad][K]. 64(k)x32(n)
// tile; packed 32-bit bf16-pair stores. Rows n>=N zeroed.
// ---------------------------------------------------------------------------
__global__ __launch_bounds__(256) void transp_bf16(
    const float* __restrict__ in, bf16* __restrict__ out, int K, int N, int Npad)
{
    __shared__ float t[64][33];
    const int n0 = blockIdx.x * 32, k0 = blockIdx.y * 64;
    const int tx = threadIdx.x, ty = threadIdx.y;
    for (int r = ty; r < 64; r += 8) {
        const int n = n0 + tx;
        t[r][tx] = (n < N) ? in[(size_t)(k0 + r) * N + n] : 0.f;
    }
    __syncthreads();
    unsigned* outu = (unsigned*)out;
    for (int r = ty; r < 32; r += 8) {
        const unsigned lo = bf16bits(t[2 * tx][r]);
        const unsigned hi = bf16bits(t[2 * tx + 1][r]);
        outu[((size_t)(n0 + r) * K + k0) / 2 + tx] = lo | (hi << 16);
    }
}

// ---------------------------------------------------------------------------
// RMSNorm v2 (vectorized, G13).
// ---------------------------------------------------------------------------
template<typename InT, typename OutT>
__global__ __launch_bounds__(256) void rmsnorm2(
    const InT* __restrict__ in, const float* __restrict__ w,
    OutT* __restrict__ out, int cols, int istride, int ostride)
{
    const int row = blockIdx.x;
    const InT* ip = in + (size_t)row * istride;
    OutT* op = out + (size_t)row * ostride;
    const int c4 = cols >> 2;

    float ss = 0.f;
    for (int c = threadIdx.x; c < c4; c += 256) {
        float4 v = ld4(ip, c);
        ss = fmaf(v.x, v.x, fmaf(v.y, v.y, fmaf(v.z, v.z, fmaf(v.w, v.w, ss))));
    }
    #pragma unroll
    for (int off = 32; off; off >>= 1) ss += __shfl_xor(ss, off);
    __shared__ float red[4];
    if ((threadIdx.x & 63) == 0) red[threadIdx.x >> 6] = ss;
    __syncthreads();
    const float total = red[0] + red[1] + red[2] + red[3];
    const float scale = rsqrtf(total / (float)cols + 1e-6f);
    for (int c = threadIdx.x; c < c4; c += 256) {
        float4 v = ld4(ip, c);
        float4 g = ((const float4*)w)[c];
        float4 o;
        o.x = v.x * scale * g.x;
        o.y = v.y * scale * g.y;
        o.z = v.z * scale * g.z;
        o.w = v.w * scale * g.w;
        st4(op, c, o);
    }
}

// ---------------------------------------------------------------------------
// Epilogue helper shared by the big GEMMs.
// ---------------------------------------------------------------------------
template<int MODE, typename OutT>
__device__ __forceinline__ void epi_store(
    OutT* __restrict__ C, const float* __restrict__ Df, const bf16* __restrict__ Db,
    int N, int row, int col, float v)
{
    const size_t off = (size_t)row * N + col;
    if (MODE == 1) v += Df[off];
    if (MODE == 2) {
        const float g = __bfloat162float(Db[off]);
        v *= g / (1.f + __expf(-g));
    }
    stf(C, off, v);
}

__device__ __forceinline__ short8_t ldsfrag(const short* half_base, int r, int c)
{
    return *(const short8_t*)(half_base + r * 64 + ((c ^ (r & 7)) << 3));
}

// ---------------------------------------------------------------------------
// 256x256 GEMM v2 (R11, proven): spread-stage, 4 phases/tile. MODE 3: kvb
// fused epilogue — d<128 -> Kh bf16 head-major; d>=128 -> fp32 C (v part).
// ---------------------------------------------------------------------------
template<int MODE, typename OutT>
__global__ __launch_bounds__(512, 2) void gemm256(
    const bf16* __restrict__ A, const bf16* __restrict__ BT,
    const float* __restrict__ Df, const bf16* __restrict__ Db,
    OutT* __restrict__ C, bf16* __restrict__ KhO, int M, int N, int K)
{
    __shared__ short lds[2][2][2][128 * 64];   // [buf][A/B][half] = 128 KiB

    const int tid = threadIdx.x;
    const int wid = tid >> 6, lane = tid & 63;
    const int wm = wid >> 2, wn = wid & 3;
    const int l16 = lane & 15, hk = lane >> 4;

    const int nwg = gridDim.x * gridDim.y;
    const int orig = blockIdx.y * gridDim.x + blockIdx.x;
    const int q = nwg >> 3, r8 = nwg & 7;
    const int xcd = orig & 7, lid = orig >> 3;
    const int wg = (xcd < r8 ? xcd * (q + 1) : r8 * (q + 1) + (xcd - r8) * q) + lid;
    const int bn = (wg % gridDim.x) * 256;
    const int bm = (wg / gridDim.x) * 256;

    f32x4 acc[8][4] = {};
    const int nt = K >> 6;

    auto stage_half = [&](const bf16* gbase, short* lbase) {
        #pragma unroll
        for (int i = 0; i < 2; ++i) {
            const int ch = i * 512 + tid;
            const int row = ch >> 3, pc = ch & 7;
            const int gc = pc ^ (row & 7);
            const char* src = (const char*)(gbase + (size_t)row * K + gc * 8);
            char* dst = (char*)lbase + (i * 512 + wid * 64) * 16;
            gload16(src, dst);
        }
    };

    stage_half(A + (size_t)bm * K,          &lds[0][0][0][0]);
    stage_half(A + (size_t)(bm + 128) * K,  &lds[0][0][1][0]);
    stage_half(BT + (size_t)bn * K,         &lds[0][1][0][0]);
    stage_half(BT + (size_t)(bn + 128) * K, &lds[0][1][1][0]);
    asm volatile("s_waitcnt vmcnt(0)" ::: "memory");
    __builtin_amdgcn_s_barrier();

    for (int t = 0; t < nt; ++t) {
        const int c = t & 1;
        const short* Ah = &lds[c][0][wm][0];
        const short* Bh = &lds[c][1][wn >> 1][0];
        const int brr = (wn & 1) * 64;
        const int k1 = (t + 1) << 6;
        const bool pf = (t + 1 < nt);

        short8_t bfr[4][2], afr[2][2];

        #pragma unroll
        for (int ph = 0; ph < 4; ++ph) {
            if (ph == 0) {
                #pragma unroll
                for (int nf = 0; nf < 4; ++nf)
                    #pragma unroll
                    for (int ks = 0; ks < 2; ++ks)
                        bfr[nf][ks] = ldsfrag(Bh, brr + nf * 16 + l16, ks * 4 + hk);
            }
            #pragma unroll
            for (int mi = 0; mi < 2; ++mi)
                #pragma unroll
                for (int ks = 0; ks < 2; ++ks)
                    afr[mi][ks] = ldsfrag(Ah, ph * 32 + mi * 16 + l16, ks * 4 + hk);
            if (pf) {
                if (ph == 0) {
                    stage_half(A + (size_t)bm * K + k1,          &lds[c ^ 1][0][0][0]);
                    stage_half(A + (size_t)(bm + 128) * K + k1,  &lds[c ^ 1][0][1][0]);
                } else if (ph == 1) {
                    stage_half(BT + (size_t)bn * K + k1,         &lds[c ^ 1][1][0][0]);
                    stage_half(BT + (size_t)(bn + 128) * K + k1, &lds[c ^ 1][1][1][0]);
                }
            }
            __builtin_amdgcn_s_setprio(1);
            #pragma unroll
            for (int mi = 0; mi < 2; ++mi)
                #pragma unroll
                for (int nf = 0; nf < 4; ++nf)
                    #pragma unroll
                    for (int ks = 0; ks < 2; ++ks)
                        acc[ph * 2 + mi][nf] = __builtin_amdgcn_mfma_f32_16x16x32_bf16(
                            afr[mi][ks], bfr[nf][ks], acc[ph * 2 + mi][nf], 0, 0, 0);
            __builtin_amdgcn_s_setprio(0);
            if (ph == 3) asm volatile("s_waitcnt vmcnt(0)" ::: "memory");
            __builtin_amdgcn_s_barrier();
        }
    }

    const int r0 = bm + wm * 128 + (lane >> 4) * 4;
    const int c0 = bn + wn * 64 + l16;
    #pragma unroll
    for (int mf = 0; mf < 8; ++mf)
        #pragma unroll
        for (int nf = 0; nf < 4; ++nf)
            #pragma unroll
            for (int r = 0; r < 4; ++r) {
                const int row = r0 + mf * 16 + r;
                const int col = c0 + nf * 16;
                float v = acc[mf][nf][r];
                if (MODE == 3) {
                    const int d = col & 255;
                    if (d < NOPE_) {
                        const int hh = col >> 8;
                        const int bb = row >> 11, s = row & 2047;
                        KhO[((size_t)(bb * NH_ + hh) * S_ + s) * QHD_ + d] = __float2bfloat16(v);
                    } else {
                        C[(size_t)row * N + col] = v;
                    }
                } else {
                    epi_store<MODE>(C, Df, Db, N, row, col, v);
                }
            }
}

// ---------------------------------------------------------------------------
// 256x128 GEMM v4 (R14, proven) — BK=64, single phase/tile.
// ---------------------------------------------------------------------------
template<int MODE, typename OutT>
__global__ __launch_bounds__(512, 2) void gemm256n128(
    const bf16* __restrict__ A, const bf16* __restrict__ BT,
    const float* __restrict__ Df, const bf16* __restrict__ Db,
    OutT* __restrict__ C, int M, int N, int K)
{
    __shared__ short lds[2][3][128 * 64];   // [buf][A0/A1/B] = 96 KiB

    const int tid = threadIdx.x;
    const int wid = tid >> 6, lane = tid & 63;
    const int wm = wid >> 1, wn = wid & 1;
    const int l16 = lane & 15, hk = lane >> 4;

    const int nwg = gridDim.x * gridDim.y;
    const int orig = blockIdx.y * gridDim.x + blockIdx.x;
    const int q = nwg >> 3, r8 = nwg & 7;
    const int xcd = orig & 7, lid = orig >> 3;
    const int wg = (xcd < r8 ? xcd * (q + 1) : r8 * (q + 1) + (xcd - r8) * q) + lid;
    const int bn = (wg % gridDim.x) * 128;
    const int bm = (wg / gridDim.x) * 256;

    f32x4 acc[4][4] = {};
    const int nt = K >> 6;

    auto stage_half = [&](const bf16* gbase, short* lbase) {
        #pragma unroll
        for (int i = 0; i < 2; ++i) {
            const int ch = i * 512 + tid;
            const int row = ch >> 3, pc = ch & 7;
            const int gc = pc ^ (row & 7);
            const char* src = (const char*)(gbase + (size_t)row * K + gc * 8);
            char* dst = (char*)lbase + (i * 512 + wid * 64) * 16;
            gload16(src, dst);
        }
    };

    stage_half(A + (size_t)bm * K,          &lds[0][0][0]);
    stage_half(A + (size_t)(bm + 128) * K,  &lds[0][1][0]);
    stage_half(BT + (size_t)bn * K,         &lds[0][2][0]);
    asm volatile("s_waitcnt vmcnt(0)" ::: "memory");
    __builtin_amdgcn_s_barrier();

    for (int t = 0; t < nt; ++t) {
        const int c = t & 1;
        const short* Ah = &lds[c][wm >> 1][0];
        const short* Bh = &lds[c][2][0];
        const int arr = (wm & 1) * 64;
        const int brr = wn * 64;
        const int k1 = (t + 1) << 6;
        const bool pf = (t + 1 < nt);

        short8_t bfr[4][2], afr[4][2];

        #pragma unroll
        for (int nf = 0; nf < 4; ++nf)
            #pragma unroll
            for (int ks = 0; ks < 2; ++ks)
                bfr[nf][ks] = ldsfrag(Bh, brr + nf * 16 + l16, ks * 4 + hk);
        #pragma unroll
        for (int mi = 0; mi < 4; ++mi)
            #pragma unroll
            for (int ks = 0; ks < 2; ++ks)
                afr[mi][ks] = ldsfrag(Ah, arr + mi * 16 + l16, ks * 4 + hk);
        if (pf) {
            stage_half(A + (size_t)bm * K + k1,         &lds[c ^ 1][0][0]);
            stage_half(A + (size_t)(bm + 128) * K + k1, &lds[c ^ 1][1][0]);
            stage_half(BT + (size_t)bn * K + k1,        &lds[c ^ 1][2][0]);
        }
        __builtin_amdgcn_s_setprio(1);
        #pragma unroll
        for (int mi = 0; mi < 4; ++mi)
            #pragma unroll
            for (int nf = 0; nf < 4; ++nf)
                #pragma unroll
                for (int ks = 0; ks < 2; ++ks)
                    acc[mi][nf] = __builtin_amdgcn_mfma_f32_16x16x32_bf16(
                        afr[mi][ks], bfr[nf][ks], acc[mi][nf], 0, 0, 0);
        __builtin_amdgcn_s_setprio(0);
        asm volatile("s_waitcnt vmcnt(0)" ::: "memory");
        __builtin_amdgcn_s_barrier();
    }

    const int r0 = bm + wm * 64 + (lane >> 4) * 4;
    const int c0 = bn + wn * 64 + l16;
    #pragma unroll
    for (int mf = 0; mf < 4; ++mf)
        #pragma unroll
        for (int nf = 0; nf < 4; ++nf)
            #pragma unroll
            for (int r = 0; r < 4; ++r)
                epi_store<MODE>(C, Df, Db, N, r0 + mf * 16 + r, c0 + nf * 16, acc[mf][nf][r]);
}

// ---------------------------------------------------------------------------
// Fused gate+up GEMM v4 (R14, proven): single phase/tile.
// ---------------------------------------------------------------------------
__global__ __launch_bounds__(512, 2) void gemm256dual(
    const bf16* __restrict__ A, const bf16* __restrict__ BG,
    const bf16* __restrict__ BU, bf16* __restrict__ C, int M, int N, int K)
{
    __shared__ short lds[2][4][128 * 64];   // [buf][A0/A1/BG/BU] = 128 KiB

    const int tid = threadIdx.x;
    const int wid = tid >> 6, lane = tid & 63;
    const int wm = wid >> 1, wn = wid & 1;
    const int l16 = lane & 15, hk = lane >> 4;

    const int nwg = gridDim.x * gridDim.y;
    const int orig = blockIdx.y * gridDim.x + blockIdx.x;
    const int q = nwg >> 3, r8 = nwg & 7;
    const int xcd = orig & 7, lid = orig >> 3;
    const int wg = (xcd < r8 ? xcd * (q + 1) : r8 * (q + 1) + (xcd - r8) * q) + lid;
    const int bm = (wg % gridDim.y) * 256;
    const int bn = (wg / gridDim.y) * 128;

    f32x4 ag[4][4] = {}, au[4][4] = {};
    const int nt = K >> 6;

    auto stage_half = [&](const bf16* gbase, short* lbase) {
        #pragma unroll
        for (int i = 0; i < 2; ++i) {
            const int ch = i * 512 + tid;
            const int row = ch >> 3, pc = ch & 7;
            const int gc = pc ^ (row & 7);
            const char* src = (const char*)(gbase + (size_t)row * K + gc * 8);
            char* dst = (char*)lbase + (i * 512 + wid * 64) * 16;
            gload16(src, dst);
        }
    };

    stage_half(A + (size_t)bm * K,          &lds[0][0][0]);
    stage_half(A + (size_t)(bm + 128) * K,  &lds[0][1][0]);
    stage_half(BG + (size_t)bn * K,         &lds[0][2][0]);
    stage_half(BU + (size_t)bn * K,         &lds[0][3][0]);
    asm volatile("s_waitcnt vmcnt(0)" ::: "memory");
    __builtin_amdgcn_s_barrier();

    for (int t = 0; t < nt; ++t) {
        const int c = t & 1;
        const short* Ah = &lds[c][wm >> 1][0];
        const short* Gs = &lds[c][2][0];
        const short* Us = &lds[c][3][0];
        const int arr = (wm & 1) * 64;
        const int brr = wn * 64;
        const int k1 = (t + 1) << 6;

        short8_t gfr[4][2], ufr[4][2], afr[4][2];

        #pragma unroll
        for (int nf = 0; nf < 4; ++nf)
            #pragma unroll
            for (int ks = 0; ks < 2; ++ks) {
                gfr[nf][ks] = ldsfrag(Gs, brr + nf * 16 + l16, ks * 4 + hk);
                ufr[nf][ks] = ldsfrag(Us, brr + nf * 16 + l16, ks * 4 + hk);
            }
        #pragma unroll
        for (int mi = 0; mi < 4; ++mi)
            #pragma unroll
            for (int ks = 0; ks < 2; ++ks)
                afr[mi][ks] = ldsfrag(Ah, arr + mi * 16 + l16, ks * 4 + hk);
        if (t + 1 < nt) {
            stage_half(A + (size_t)bm * K + k1,         &lds[c ^ 1][0][0]);
            stage_half(A + (size_t)(bm + 128) * K + k1, &lds[c ^ 1][1][0]);
            stage_half(BG + (size_t)bn * K + k1,        &lds[c ^ 1][2][0]);
            stage_half(BU + (size_t)bn * K + k1,        &lds[c ^ 1][3][0]);
        }
        __builtin_amdgcn_s_setprio(1);
        #pragma unroll
        for (int mi = 0; mi < 4; ++mi)
            #pragma unroll
            for (int nf = 0; nf < 4; ++nf)
                #pragma unroll
                for (int ks = 0; ks < 2; ++ks) {
                    ag[mi][nf] = __builtin_amdgcn_mfma_f32_16x16x32_bf16(
                        afr[mi][ks], gfr[nf][ks], ag[mi][nf], 0, 0, 0);
                    au[mi][nf] = __builtin_amdgcn_mfma_f32_16x16x32_bf16(
                        afr[mi][ks], ufr[nf][ks], au[mi][nf], 0, 0, 0);
                }
        __builtin_amdgcn_s_setprio(0);

        asm volatile("s_waitcnt vmcnt(0)" ::: "memory");
        __builtin_amdgcn_s_barrier();
    }

    const int r0 = bm + wm * 64 + (lane >> 4) * 4;
    const int c0 = bn + wn * 64 + l16;
    #pragma unroll
    for (int mf = 0; mf < 4; ++mf)
        #pragma unroll
        for (int nf = 0; nf < 4; ++nf)
            #pragma unroll
            for (int r = 0; r < 4; ++r) {
                const float gg = ag[mf][nf][r];
                const float uu = au[mf][nf][r];
                const float v = gg / (1.f + __expf(-gg)) * uu;
                C[(size_t)(r0 + mf * 16 + r) * N + c0 + nf * 16] = __float2bfloat16(v);
            }
}

// ---------------------------------------------------------------------------
// RoPE v2: q_pe in place; k_pe -> all 16 heads' Kh[...][128:192].
// ---------------------------------------------------------------------------
__global__ __launch_bounds__(256) void rope_kernel(
    bf16* __restrict__ q, const float* __restrict__ ckv,
    bf16* __restrict__ Kh, const int* __restrict__ pos_ids,
    const float* __restrict__ sinT, const float* __restrict__ cosT)
{
    const int wid = blockIdx.x * 4 + (threadIdx.x >> 6);
    const int lane = threadIdx.x & 63;
    const int NQ = BS_ * NH_;

    int bs;
    float x;
    bf16* bptr = nullptr;
    if (wid < NQ) {
        bs = wid >> 4;
        bptr = q + (size_t)wid * QHD_ + NOPE_;
        x = __bfloat162float(bptr[lane]);
    } else {
        bs = wid - NQ;
        x = ckv[(size_t)bs * CKVP_ + KVL_ + lane];
    }
    const int pos = pos_ids[bs];
    const float c  = cosT[pos * ROPE_ + lane];
    const float sn = sinT[pos * ROPE_ + lane];
    const int j = lane & 31;
    const float x0 = __shfl(x, 2 * j);
    const float x1 = __shfl(x, 2 * j + 1);
    const float res = (lane < 32) ? fmaf(x0, c, -x1 * sn) : fmaf(x1, c, x0 * sn);
    if (bptr) {
        bptr[lane] = __float2bfloat16(res);
    } else {
        const int bb = bs >> 11, s = bs & 2047;
        const bf16 rv = __float2bfloat16(res);
        #pragma unroll
        for (int hh = 0; hh < NH_; ++hh)
            Kh[((size_t)(bb * NH_ + hh) * S_ + s) * QHD_ + NOPE_ + lane] = rv;
    }
}

// ---------------------------------------------------------------------------
// pack_vt: Vt (B,NH,128,S) bf16 <- V = KV[...,128:256] fp32, transposed.
// ---------------------------------------------------------------------------
__global__ __launch_bounds__(256) void pack_vt(
    const float* __restrict__ KV, bf16* __restrict__ Vt)
{
    __shared__ float t[32][33];
    const int s0 = blockIdx.x * 32, d0 = blockIdx.y * 32;
    const int bh = blockIdx.z;
    const int tx = threadIdx.x & 31, ty = threadIdx.x >> 5;
    for (int r = ty; r < 32; r += 8)
        t[r][tx] = KV[(((size_t)(bh >> 4) * S_ + s0 + r) * NH_ + (bh & 15)) * KVW_ + NOPE_ + d0 + tx];
    __syncthreads();
    for (int r = ty; r < 32; r += 8)
        Vt[((size_t)bh * VHD_ + d0 + r) * S_ + s0 + tx] = __float2bfloat16(t[tx][r]);
}

// ---------------------------------------------------------------------------
// MFMA flash attention v5 (R15, proven) — double-buffered K/V LDS, one
// barrier per tile, launch_bounds(512,2) (honest ~170 VGPR, no spill).
// ---------------------------------------------------------------------------
__global__ __launch_bounds__(512, 2) void attn_mfma(
    const bf16* __restrict__ Qp, const bf16* __restrict__ Kh,
    const bf16* __restrict__ Vt, bf16* __restrict__ outp)
{
    __shared__ __align__(16) short Ks[2][64][192];
    __shared__ __align__(16) short Vs[2][128][64];
    __shared__ __align__(16) short Ps[8][16][64];

    const int tid = threadIdx.x;
    const int wid = tid >> 6, lane = tid & 63;
    const int l16 = lane & 15;
    const int hk  = lane >> 4;
    const int lk  = hk << 3;
    const int pr  = hk << 2;
    const int lx  = l16 & 7;

    const int bid = blockIdx.x;
    const int orig = (bid & 7) * 64 + (bid >> 3);
    const int j  = orig & 15;
    const int gh = orig >> 4;
    const int h = gh & 15, b = gh >> 4;

    const int setB = wid >> 2;
    const int qblk = setB ? (31 - j) : j;
    const int qw = qblk * 64 + (wid & 3) * 16;
    const int myNt = qblk + 1;
    const int ntStage = 32 - j;

    short8_t qf[6];
    const bf16* qbase = Qp + (((size_t)b * S_ + qw + l16) * NH_ + h) * QHD_;
    #pragma unroll
    for (int kk = 0; kk < 6; ++kk)
        qf[kk] = *(const short8_t*)(qbase + kk * 32 + lk);

    const bf16* Khb = Kh + (size_t)(b * NH_ + h) * S_ * QHD_;
    const bf16* Vtb = Vt + (size_t)(b * NH_ + h) * VHD_ * S_;

    f32x4 o[8] = {};
    float mr[4] = {-3.0e38f, -3.0e38f, -3.0e38f, -3.0e38f};
    float lr[4] = {0.f, 0.f, 0.f, 0.f};
    const float scale = 0.07216878364870323f;

    const int krow = tid >> 3, kc0 = (tid & 7) * 3;
    const int vrow = tid >> 2, vc0 = (tid & 3) * 2;

    short8_t kreg[3], vreg[2];
    auto load_tile = [&](int kt) {
        const short* ksrc = (const short*)(Khb + ((size_t)(kt * 64 + krow)) * QHD_);
        kreg[0] = *(const short8_t*)(ksrc + (kc0 + 0) * 8);
        kreg[1] = *(const short8_t*)(ksrc + (kc0 + 1) * 8);
        kreg[2] = *(const short8_t*)(ksrc + (kc0 + 2) * 8);
        const short* vsrc = (const short*)(Vtb + (size_t)vrow * S_ + kt * 64);
        vreg[0] = *(const short8_t*)(vsrc + (vc0 + 0) * 8);
        vreg[1] = *(const short8_t*)(vsrc + (vc0 + 1) * 8);
    };
    auto write_tile = [&](int buf) {
        const int kx = krow & 7, vx = vrow & 7;
        *(short8_t*)&Ks[buf][krow][((kc0 + 0) ^ kx) << 3] = kreg[0];
        *(short8_t*)&Ks[buf][krow][((kc0 + 1) ^ kx) << 3] = kreg[1];
        *(short8_t*)&Ks[buf][krow][((kc0 + 2) ^ kx) << 3] = kreg[2];
        *(short8_t*)&Vs[buf][vrow][((vc0 + 0) ^ vx) << 3] = vreg[0];
        *(short8_t*)&Vs[buf][vrow][((vc0 + 1) ^ vx) << 3] = vreg[1];
    };

    load_tile(0);
    write_tile(0);
    __syncthreads();

    for (int t = 0; t < ntStage; ++t) {
        const int cb = t & 1;
        if (t + 1 < ntStage) load_tile(t + 1);
        if (t < myNt) {
            const int k0 = t << 6;
            f32x4 s[4] = {};
            #pragma unroll
            for (int kk = 0; kk < 6; ++kk) {
                #pragma unroll
                for (int n = 0; n < 4; ++n) {
                    short8_t kf = *(const short8_t*)&Ks[cb][n * 16 + l16][((kk * 4 + hk) ^ lx) << 3];
                    s[n] = __builtin_amdgcn_mfma_f32_16x16x32_bf16(qf[kk], kf, s[n], 0, 0, 0);
                }
            }
            if (t == myNt - 1) {
                #pragma unroll
                for (int n = 0; n < 4; ++n) {
                    const int kg = k0 + n * 16 + l16;
                    #pragma unroll
                    for (int r = 0; r < 4; ++r) {
                        if (kg > qw + pr + r) s[n][r] = -3.0e38f;
                    }
                }
            }
            #pragma unroll
            for (int r = 0; r < 4; ++r) {
                float rm = fmaxf(fmaxf(s[0][r], s[1][r]), fmaxf(s[2][r], s[3][r]));
                rm = fmaxf(rm, __shfl_xor(rm, 1));
                rm = fmaxf(rm, __shfl_xor(rm, 2));
                rm = fmaxf(rm, __shfl_xor(rm, 4));
                rm = fmaxf(rm, __shfl_xor(rm, 8));
                const float mnew = fmaxf(mr[r], rm);
                const float corr = __expf((mr[r] - mnew) * scale);
                mr[r] = mnew;
                float rs = 0.f;
                #pragma unroll
                for (int n = 0; n < 4; ++n) {
                    const float p = __expf((s[n][r] - mnew) * scale);
                    s[n][r] = p;
                    rs += p;
                }
                rs += __shfl_xor(rs, 1);
                rs += __shfl_xor(rs, 2);
                rs += __shfl_xor(rs, 4);
                rs += __shfl_xor(rs, 8);
                lr[r] = lr[r] * corr + rs;
                #pragma unroll
                for (int n = 0; n < 8; ++n) o[n][r] *= corr;
            }
            #pragma unroll
            for (int n = 0; n < 4; ++n) {
                #pragma unroll
                for (int r = 0; r < 4; ++r) {
                    union { bf16 hh; short u; } cv;
                    cv.hh = __float2bfloat16(s[n][r]);
                    const int row = pr + r;
                    const int col = (((n * 2 + (l16 >> 3)) ^ (row & 7)) << 3) + (l16 & 7);
                    Ps[wid][row][col] = cv.u;
                }
            }
            #pragma unroll
            for (int kk2 = 0; kk2 < 2; ++kk2) {
                short8_t pf = *(const short8_t*)&Ps[wid][l16][((kk2 * 4 + hk) ^ lx) << 3];
                #pragma unroll
                for (int n = 0; n < 8; ++n) {
                    short8_t vf = *(const short8_t*)&Vs[cb][n * 16 + l16][((kk2 * 4 + hk) ^ lx) << 3];
                    o[n] = __builtin_amdgcn_mfma_f32_16x16x32_bf16(pf, vf, o[n], 0, 0, 0);
                }
            }
        }
        if (t + 1 < ntStage) write_tile((t + 1) & 1);
        __syncthreads();
    }

    float inv[4];
    #pragma unroll
    for (int r = 0; r < 4; ++r) inv[r] = 1.f / lr[r];
    bf16* ob = outp + (((size_t)b * S_ + qw + pr) * NH_ + h) * VHD_;
    #pragma unroll
    for (int r = 0; r < 4; ++r)
        #pragma unroll
        for (int n = 0; n < 8; ++n)
            ob[(size_t)r * (NH_ * VHD_) + n * 16 + l16] = __float2bfloat16(o[n][r] * inv[r]);
}

// ---------------------------------------------------------------------------
// Launch
// ---------------------------------------------------------------------------
extern "C" void kernel_launch(void* const* d_in, const int* in_sizes, int n_in,
                              void* d_out, int out_size, void* d_ws, size_t ws_size,
                              hipStream_t stream)
{
    const float* hidden  = (const float*)d_in[0];
    const float* ln1_w   = (const float*)d_in[1];
    const float* q_a_k   = (const float*)d_in[2];
    const float* q_a_ln  = (const float*)d_in[3];
    const float* q_b_k   = (const float*)d_in[4];
    const float* kv_a_k  = (const float*)d_in[5];
    const float* kv_a_ln = (const float*)d_in[6];
    const float* kv_b_k  = (const float*)d_in[7];
    const float* o_k     = (const float*)d_in[8];
    const float* ln2_w   = (const float*)d_in[9];
    const float* gate_k  = (const float*)d_in[10];
    const float* up_k    = (const float*)d_in[11];
    const float* down_k  = (const float*)d_in[12];
    const float* sinT    = (const float*)d_in[13];
    const float* cosT    = (const float*)d_in[14];
    const int*   pos     = (const int*)d_in[15];
    float* out = (float*)d_out;
    char* ws = (char*)d_ws;

    // ---- Phase-1 workspace layout ----
    bf16* qaT   = (bf16*)(ws + 0);            // [1536][2048]  6,291,456
    bf16* qbT   = (bf16*)(ws + 6291456);      // [3072][1536]  9,437,184
    bf16* kvaT  = (bf16*)(ws + 15728640);     // [640][2048]   2,621,440
    bf16* kvbT  = (bf16*)(ws + 18350080);     // [4096][512]   4,194,304
    bf16* oT    = (bf16*)(ws + 22544384);     // [2048][2048]  8,388,608
    bf16* Xb    = (bf16*)(ws + 30932992);     // [4096][2048] 16,777,216
    bf16* QAb   = (bf16*)(ws + 47710208);     // [4096][1536] 12,582,912
    bf16* CKVNb = (bf16*)(ws + 60293120);     // [4096][512]   4,194,304
    bf16* Qb    = (bf16*)(ws + 64487424);     // [4096][3072] 25,165,824
    float* CKV  = (float*)(ws + 89653248);    // [4096][640]  10,485,760
    float* KV   = (float*)(ws + 100139008);   // [4096][4096] 67,108,864
    bf16* ATTNb = (bf16*)(ws + 167247872);    // [4096][2048] 16,777,216
    bf16* Vt    = (bf16*)(ws + 0);            // overlays dead qaT/qbT/kvaT
    bf16* Kh    = (bf16*)(ws + 30932992);     // overlays dead Xb+QAb(part)
    // ---- Phase-2 layout ----
    bf16* gateT = (bf16*)(ws + 0);            // [8192][2048] 33,554,432
    bf16* upT   = (bf16*)(ws + 33554432);     // [8192][2048] 33,554,432
    bf16* downT = (bf16*)(ws + 67108864);     // [2048][8192] 33,554,432
    bf16* X2b   = (bf16*)(ws + 100663296);    // [4096][2048] 16,777,216
    bf16* MLPb  = (bf16*)(ws + 117440512);    // [4096][8192] 67,108,864

    const dim3 tb(32, 8);

    // 0. weight transposes (attention-phase weights); grid (Npad/32, K/64)
    transp_bf16<<<dim3(1536 / 32, 2048 / 64), tb, 0, stream>>>(q_a_k, qaT, 2048, 1536, 1536);
    transp_bf16<<<dim3(3072 / 32, 1536 / 64), tb, 0, stream>>>(q_b_k, qbT, 1536, 3072, 3072);
    transp_bf16<<<dim3(640 / 32, 2048 / 64), tb, 0, stream>>>(kv_a_k, kvaT, 2048, 576, 640);
    transp_bf16<<<dim3(4096 / 32, 512 / 64), tb, 0, stream>>>(kv_b_k, kvbT, 512, 4096, 4096);
    transp_bf16<<<dim3(2048 / 32, 2048 / 64), tb, 0, stream>>>(o_k, oT, 2048, 2048, 2048);

    // 1. Xb = rmsnorm(hidden)
    rmsnorm2<float, bf16><<<BS_, 256, 0, stream>>>(hidden, ln1_w, Xb, H_, H_, H_);
    // 2. QAb = Xb @ qaT   (n128 v4, grid 12x16)
    gemm256n128<0, bf16><<<dim3(QL_ / 128, BS_ / 256), 512, 0, stream>>>(
        Xb, qaT, nullptr, nullptr, QAb, BS_, QL_, H_);
    // 3. QAb = rmsnorm(QAb) in place
    rmsnorm2<bf16, bf16><<<BS_, 256, 0, stream>>>(QAb, q_a_ln, QAb, QL_, QL_, QL_);
    // 4. Qb = QAb @ qbT   (n128 v4, grid 24x16)
    gemm256n128<0, bf16><<<dim3((NH_ * QHD_) / 128, BS_ / 256), 512, 0, stream>>>(
        QAb, qbT, nullptr, nullptr, Qb, BS_, NH_ * QHD_, QL_);
    // 5. CKV = Xb @ kvaT (fp32, padded width 640; n128 v4, grid 5x16)
    gemm256n128<0, float><<<dim3(CKVP_ / 128, BS_ / 256), 512, 0, stream>>>(
        Xb, kvaT, nullptr, nullptr, CKV, BS_, CKVP_, H_);
    // 6. CKVNb = rmsnorm(CKV[:, :512])
    rmsnorm2<float, bf16><<<BS_, 256, 0, stream>>>(CKV, kv_a_ln, CKVNb, KVL_, CKVP_, KVL_);
    // 7. KV/Kh = CKVNb @ kvbT (MODE 3: k_nope -> Kh bf16, v -> KV fp32)
    gemm256<3, float><<<dim3((NH_ * KVW_) / 256, BS_ / 256), 512, 0, stream>>>(
        CKVNb, kvbT, nullptr, nullptr, KV, Kh, BS_, NH_ * KVW_, KVL_);
    // 8. RoPE: q_pe in place; k_pe -> Kh[*][128:192] for all heads
    rope_kernel<<<(BS_ * NH_ + BS_) / 4, 256, 0, stream>>>(Qb, CKV, Kh, pos, sinT, cosT);
    // 9. pack V^T (bf16 transposed)
    pack_vt<<<dim3(S_ / 32, VHD_ / 32, B_ * NH_), 256, 0, stream>>>(KV, Vt);
    // 10. MFMA flash attention v5 -> ATTNb
    attn_mfma<<<dim3(512), 512, 0, stream>>>(Qb, Kh, Vt, ATTNb);
    // 11. d_out = ATTNb @ oT + hidden (fp32, n128 v4, grid 16x16)
    gemm256n128<1, float><<<dim3(H_ / 128, BS_ / 256), 512, 0, stream>>>(
        ATTNb, oT, hidden, nullptr, out, BS_, H_, NH_ * VHD_);

    // 12. MLP-phase weight transposes
    transp_bf16<<<dim3(8192 / 32, 2048 / 64), tb, 0, stream>>>(gate_k, gateT, 2048, 8192, 8192);
    transp_bf16<<<dim3(8192 / 32, 2048 / 64), tb, 0, stream>>>(up_k, upT, 2048, 8192, 8192);
    transp_bf16<<<dim3(2048 / 32, 8192 / 64), tb, 0, stream>>>(down_k, downT, 8192, 2048, 2048);

    // 13. X2b = rmsnorm(d_out)
    rmsnorm2<float, bf16><<<BS_, 256, 0, stream>>>(out, ln2_w, X2b, H_, H_, H_);
    // 14. MLPb = silu(X2b @ gateT) * (X2b @ upT)  — fused dual GEMM (v4)
    gemm256dual<<<dim3(FF_ / 128, BS_ / 256), 512, 0, stream>>>(
        X2b, gateT, upT, MLPb, BS_, FF_, H_);
    // 15. d_out = MLPb @ downT + d_out (n128 v4, grid 16x16)
    gemm256n128<1, float><<<dim3(H_ / 128, BS_ / 256), 512, 0, stream>>>(
        MLPb, downT, out, nullptr, out, BS_, H_, FF_);
}

// Round 21
// 881.856 us; speedup vs baseline: 1.1736x; 1.0181x over previous
//
#include <hip/hip_runtime.h>
#include <hip/hip_bf16.h>
#include <cstdint>

#define B_ 2
#define S_ 2048
#define H_ 2048
#define NH_ 16
#define QL_ 1536
#define KVL_ 512
#define NOPE_ 128
#define ROPE_ 64
#define QHD_ 192
#define VHD_ 128
#define FF_ 8192
#define BS_ (B_ * S_)            // 4096 rows
#define CKVP_ 640                // padded ckv width (576 -> 640 for N%128==0)
#define KVW_ (NOPE_ + VHD_)      // 256 per head

typedef __hip_bfloat16 bf16;
typedef __attribute__((ext_vector_type(8))) short short8_t;  // 8 bf16 (4 VGPRs)
typedef __attribute__((ext_vector_type(4))) float f32x4;

__device__ __forceinline__ float ldf(const float* p, size_t i) { return p[i]; }
__device__ __forceinline__ float ldf(const bf16* p, size_t i) { return __bfloat162float(p[i]); }
__device__ __forceinline__ void stf(float* p, size_t i, float v) { p[i] = v; }
__device__ __forceinline__ void stf(bf16* p, size_t i, float v) { p[i] = __float2bfloat16(v); }

__device__ __forceinline__ unsigned short bf16bits(float x)
{
    union { bf16 h; unsigned short u; } c;
    c.h = __float2bfloat16(x);
    return c.u;
}

// vectorized 4-wide load/store helpers (G13)
__device__ __forceinline__ float4 ld4(const float* p, int i)
{
    return ((const float4*)p)[i];
}
__device__ __forceinline__ float4 ld4(const bf16* p, int i)
{
    ushort4 u = *(const ushort4*)((const unsigned short*)p + i * 4);
    float4 v;
    v.x = __uint_as_float((unsigned)u.x << 16);
    v.y = __uint_as_float((unsigned)u.y << 16);
    v.z = __uint_as_float((unsigned)u.z << 16);
    v.w = __uint_as_float((unsigned)u.w << 16);
    return v;
}
__device__ __forceinline__ void st4(float* p, int i, float4 v)
{
    ((float4*)p)[i] = v;
}
__device__ __forceinline__ void st4(bf16* p, int i, float4 v)
{
    ushort4 u;
    u.x = bf16bits(v.x); u.y = bf16bits(v.y);
    u.z = bf16bits(v.z); u.w = bf16bits(v.w);
    *(ushort4*)((unsigned short*)p + i * 4) = u;
}

__device__ __forceinline__ void gload16(const void* g, void* l)
{
    __builtin_amdgcn_global_load_lds((const unsigned int*)g, (unsigned int*)l, 16, 0, 0);
}

// ---------------------------------------------------------------------------
// Transpose + convert v2: in fp32 [K][N] -> out bf16 [Npad][K]. 64(k)x32(n)
// tile; packed 32-bit bf16-pair stores. Rows n>=N zeroed.
// ---------------------------------------------------------------------------
__global__ __launch_bounds__(256) void transp_bf16(
    const float* __restrict__ in, bf16* __restrict__ out, int K, int N, int Npad)
{
    __shared__ float t[64][33];
    const int n0 = blockIdx.x * 32, k0 = blockIdx.y * 64;
    const int tx = threadIdx.x, ty = threadIdx.y;
    for (int r = ty; r < 64; r += 8) {
        const int n = n0 + tx;
        t[r][tx] = (n < N) ? in[(size_t)(k0 + r) * N + n] : 0.f;
    }
    __syncthreads();
    unsigned* outu = (unsigned*)out;
    for (int r = ty; r < 32; r += 8) {
        const unsigned lo = bf16bits(t[2 * tx][r]);
        const unsigned hi = bf16bits(t[2 * tx + 1][r]);
        outu[((size_t)(n0 + r) * K + k0) / 2 + tx] = lo | (hi << 16);
    }
}

// ---------------------------------------------------------------------------
// RMSNorm v2 (vectorized, G13).
// ---------------------------------------------------------------------------
template<typename InT, typename OutT>
__global__ __launch_bounds__(256) void rmsnorm2(
    const InT* __restrict__ in, const float* __restrict__ w,
    OutT* __restrict__ out, int cols, int istride, int ostride)
{
    const int row = blockIdx.x;
    const InT* ip = in + (size_t)row * istride;
    OutT* op = out + (size_t)row * ostride;
    const int c4 = cols >> 2;

    float ss = 0.f;
    for (int c = threadIdx.x; c < c4; c += 256) {
        float4 v = ld4(ip, c);
        ss = fmaf(v.x, v.x, fmaf(v.y, v.y, fmaf(v.z, v.z, fmaf(v.w, v.w, ss))));
    }
    #pragma unroll
    for (int off = 32; off; off >>= 1) ss += __shfl_xor(ss, off);
    __shared__ float red[4];
    if ((threadIdx.x & 63) == 0) red[threadIdx.x >> 6] = ss;
    __syncthreads();
    const float total = red[0] + red[1] + red[2] + red[3];
    const float scale = rsqrtf(total / (float)cols + 1e-6f);
    for (int c = threadIdx.x; c < c4; c += 256) {
        float4 v = ld4(ip, c);
        float4 g = ((const float4*)w)[c];
        float4 o;
        o.x = v.x * scale * g.x;
        o.y = v.y * scale * g.y;
        o.z = v.z * scale * g.z;
        o.w = v.w * scale * g.w;
        st4(op, c, o);
    }
}

// ---------------------------------------------------------------------------
// Epilogue helper shared by the big GEMMs.
// ---------------------------------------------------------------------------
template<int MODE, typename OutT>
__device__ __forceinline__ void epi_store(
    OutT* __restrict__ C, const float* __restrict__ Df, const bf16* __restrict__ Db,
    int N, int row, int col, float v)
{
    const size_t off = (size_t)row * N + col;
    if (MODE == 1) v += Df[off];
    if (MODE == 2) {
        const float g = __bfloat162float(Db[off]);
        v *= g / (1.f + __expf(-g));
    }
    stf(C, off, v);
}

__device__ __forceinline__ short8_t ldsfrag(const short* half_base, int r, int c)
{
    return *(const short8_t*)(half_base + r * 64 + ((c ^ (r & 7)) << 3));
}

// ---------------------------------------------------------------------------
// 256x256 GEMM v2 (R11, proven): spread-stage, 4 phases/tile. MODE 3: kvb
// fused epilogue — d<128 -> Kh bf16 head-major; d>=128 -> Vt bf16 DIRECT
// TRANSPOSED (4 consecutive s at fixed d = one ushort4). Kills pack_vt.
// ---------------------------------------------------------------------------
template<int MODE, typename OutT>
__global__ __launch_bounds__(512, 2) void gemm256(
    const bf16* __restrict__ A, const bf16* __restrict__ BT,
    const float* __restrict__ Df, const bf16* __restrict__ Db,
    OutT* __restrict__ C, bf16* __restrict__ KhO, bf16* __restrict__ VtO,
    int M, int N, int K)
{
    __shared__ short lds[2][2][2][128 * 64];   // [buf][A/B][half] = 128 KiB

    const int tid = threadIdx.x;
    const int wid = tid >> 6, lane = tid & 63;
    const int wm = wid >> 2, wn = wid & 3;
    const int l16 = lane & 15, hk = lane >> 4;

    const int nwg = gridDim.x * gridDim.y;
    const int orig = blockIdx.y * gridDim.x + blockIdx.x;
    const int q = nwg >> 3, r8 = nwg & 7;
    const int xcd = orig & 7, lid = orig >> 3;
    const int wg = (xcd < r8 ? xcd * (q + 1) : r8 * (q + 1) + (xcd - r8) * q) + lid;
    const int bn = (wg % gridDim.x) * 256;
    const int bm = (wg / gridDim.x) * 256;

    f32x4 acc[8][4] = {};
    const int nt = K >> 6;

    auto stage_half = [&](const bf16* gbase, short* lbase) {
        #pragma unroll
        for (int i = 0; i < 2; ++i) {
            const int ch = i * 512 + tid;
            const int row = ch >> 3, pc = ch & 7;
            const int gc = pc ^ (row & 7);
            const char* src = (const char*)(gbase + (size_t)row * K + gc * 8);
            char* dst = (char*)lbase + (i * 512 + wid * 64) * 16;
            gload16(src, dst);
        }
    };

    stage_half(A + (size_t)bm * K,          &lds[0][0][0][0]);
    stage_half(A + (size_t)(bm + 128) * K,  &lds[0][0][1][0]);
    stage_half(BT + (size_t)bn * K,         &lds[0][1][0][0]);
    stage_half(BT + (size_t)(bn + 128) * K, &lds[0][1][1][0]);
    asm volatile("s_waitcnt vmcnt(0)" ::: "memory");
    __builtin_amdgcn_s_barrier();

    for (int t = 0; t < nt; ++t) {
        const int c = t & 1;
        const short* Ah = &lds[c][0][wm][0];
        const short* Bh = &lds[c][1][wn >> 1][0];
        const int brr = (wn & 1) * 64;
        const int k1 = (t + 1) << 6;
        const bool pf = (t + 1 < nt);

        short8_t bfr[4][2], afr[2][2];

        #pragma unroll
        for (int ph = 0; ph < 4; ++ph) {
            if (ph == 0) {
                #pragma unroll
                for (int nf = 0; nf < 4; ++nf)
                    #pragma unroll
                    for (int ks = 0; ks < 2; ++ks)
                        bfr[nf][ks] = ldsfrag(Bh, brr + nf * 16 + l16, ks * 4 + hk);
            }
            #pragma unroll
            for (int mi = 0; mi < 2; ++mi)
                #pragma unroll
                for (int ks = 0; ks < 2; ++ks)
                    afr[mi][ks] = ldsfrag(Ah, ph * 32 + mi * 16 + l16, ks * 4 + hk);
            if (pf) {
                if (ph == 0) {
                    stage_half(A + (size_t)bm * K + k1,          &lds[c ^ 1][0][0][0]);
                    stage_half(A + (size_t)(bm + 128) * K + k1,  &lds[c ^ 1][0][1][0]);
                } else if (ph == 1) {
                    stage_half(BT + (size_t)bn * K + k1,         &lds[c ^ 1][1][0][0]);
                    stage_half(BT + (size_t)(bn + 128) * K + k1, &lds[c ^ 1][1][1][0]);
                }
            }
            __builtin_amdgcn_s_setprio(1);
            #pragma unroll
            for (int mi = 0; mi < 2; ++mi)
                #pragma unroll
                for (int nf = 0; nf < 4; ++nf)
                    #pragma unroll
                    for (int ks = 0; ks < 2; ++ks)
                        acc[ph * 2 + mi][nf] = __builtin_amdgcn_mfma_f32_16x16x32_bf16(
                            afr[mi][ks], bfr[nf][ks], acc[ph * 2 + mi][nf], 0, 0, 0);
            __builtin_amdgcn_s_setprio(0);
            if (ph == 3) asm volatile("s_waitcnt vmcnt(0)" ::: "memory");
            __builtin_amdgcn_s_barrier();
        }
    }

    const int r0 = bm + wm * 128 + (lane >> 4) * 4;
    const int c0 = bn + wn * 64 + l16;
    #pragma unroll
    for (int mf = 0; mf < 8; ++mf)
        #pragma unroll
        for (int nf = 0; nf < 4; ++nf) {
            const int row0 = r0 + mf * 16;
            const int col = c0 + nf * 16;
            if (MODE == 3) {
                const int d = col & 255;
                const int hh = col >> 8;
                const int bb = row0 >> 11, s0q = row0 & 2047;
                if (d < NOPE_) {
                    #pragma unroll
                    for (int r = 0; r < 4; ++r)
                        KhO[((size_t)(bb * NH_ + hh) * S_ + s0q + r) * QHD_ + d] =
                            __float2bfloat16(acc[mf][nf][r]);
                } else {
                    ushort4 u;
                    u.x = bf16bits(acc[mf][nf][0]);
                    u.y = bf16bits(acc[mf][nf][1]);
                    u.z = bf16bits(acc[mf][nf][2]);
                    u.w = bf16bits(acc[mf][nf][3]);
                    *(ushort4*)((unsigned short*)VtO +
                        ((size_t)(bb * NH_ + hh) * VHD_ + (d - NOPE_)) * S_ + s0q) = u;
                }
            } else {
                #pragma unroll
                for (int r = 0; r < 4; ++r)
                    epi_store<MODE>(C, Df, Db, N, row0 + r, col, acc[mf][nf][r]);
            }
        }
}

// ---------------------------------------------------------------------------
// 256x128 GEMM v4 (R14, proven) — BK=64, single phase/tile.
// ---------------------------------------------------------------------------
template<int MODE, typename OutT>
__global__ __launch_bounds__(512, 2) void gemm256n128(
    const bf16* __restrict__ A, const bf16* __restrict__ BT,
    const float* __restrict__ Df, const bf16* __restrict__ Db,
    OutT* __restrict__ C, int M, int N, int K)
{
    __shared__ short lds[2][3][128 * 64];   // [buf][A0/A1/B] = 96 KiB

    const int tid = threadIdx.x;
    const int wid = tid >> 6, lane = tid & 63;
    const int wm = wid >> 1, wn = wid & 1;
    const int l16 = lane & 15, hk = lane >> 4;

    const int nwg = gridDim.x * gridDim.y;
    const int orig = blockIdx.y * gridDim.x + blockIdx.x;
    const int q = nwg >> 3, r8 = nwg & 7;
    const int xcd = orig & 7, lid = orig >> 3;
    const int wg = (xcd < r8 ? xcd * (q + 1) : r8 * (q + 1) + (xcd - r8) * q) + lid;
    const int bn = (wg % gridDim.x) * 128;
    const int bm = (wg / gridDim.x) * 256;

    f32x4 acc[4][4] = {};
    const int nt = K >> 6;

    auto stage_half = [&](const bf16* gbase, short* lbase) {
        #pragma unroll
        for (int i = 0; i < 2; ++i) {
            const int ch = i * 512 + tid;
            const int row = ch >> 3, pc = ch & 7;
            const int gc = pc ^ (row & 7);
            const char* src = (const char*)(gbase + (size_t)row * K + gc * 8);
            char* dst = (char*)lbase + (i * 512 + wid * 64) * 16;
            gload16(src, dst);
        }
    };

    stage_half(A + (size_t)bm * K,          &lds[0][0][0]);
    stage_half(A + (size_t)(bm + 128) * K,  &lds[0][1][0]);
    stage_half(BT + (size_t)bn * K,         &lds[0][2][0]);
    asm volatile("s_waitcnt vmcnt(0)" ::: "memory");
    __builtin_amdgcn_s_barrier();

    for (int t = 0; t < nt; ++t) {
        const int c = t & 1;
        const short* Ah = &lds[c][wm >> 1][0];
        const short* Bh = &lds[c][2][0];
        const int arr = (wm & 1) * 64;
        const int brr = wn * 64;
        const int k1 = (t + 1) << 6;
        const bool pf = (t + 1 < nt);

        short8_t bfr[4][2], afr[4][2];

        #pragma unroll
        for (int nf = 0; nf < 4; ++nf)
            #pragma unroll
            for (int ks = 0; ks < 2; ++ks)
                bfr[nf][ks] = ldsfrag(Bh, brr + nf * 16 + l16, ks * 4 + hk);
        #pragma unroll
        for (int mi = 0; mi < 4; ++mi)
            #pragma unroll
            for (int ks = 0; ks < 2; ++ks)
                afr[mi][ks] = ldsfrag(Ah, arr + mi * 16 + l16, ks * 4 + hk);
        if (pf) {
            stage_half(A + (size_t)bm * K + k1,         &lds[c ^ 1][0][0]);
            stage_half(A + (size_t)(bm + 128) * K + k1, &lds[c ^ 1][1][0]);
            stage_half(BT + (size_t)bn * K + k1,        &lds[c ^ 1][2][0]);
        }
        __builtin_amdgcn_s_setprio(1);
        #pragma unroll
        for (int mi = 0; mi < 4; ++mi)
            #pragma unroll
            for (int nf = 0; nf < 4; ++nf)
                #pragma unroll
                for (int ks = 0; ks < 2; ++ks)
                    acc[mi][nf] = __builtin_amdgcn_mfma_f32_16x16x32_bf16(
                        afr[mi][ks], bfr[nf][ks], acc[mi][nf], 0, 0, 0);
        __builtin_amdgcn_s_setprio(0);
        asm volatile("s_waitcnt vmcnt(0)" ::: "memory");
        __builtin_amdgcn_s_barrier();
    }

    const int r0 = bm + wm * 64 + (lane >> 4) * 4;
    const int c0 = bn + wn * 64 + l16;
    #pragma unroll
    for (int mf = 0; mf < 4; ++mf)
        #pragma unroll
        for (int nf = 0; nf < 4; ++nf)
            #pragma unroll
            for (int r = 0; r < 4; ++r)
                epi_store<MODE>(C, Df, Db, N, r0 + mf * 16 + r, c0 + nf * 16, acc[mf][nf][r]);
}

// ---------------------------------------------------------------------------
// Fused gate+up GEMM v4 (R14, proven): single phase/tile.
// ---------------------------------------------------------------------------
__global__ __launch_bounds__(512, 2) void gemm256dual(
    const bf16* __restrict__ A, const bf16* __restrict__ BG,
    const bf16* __restrict__ BU, bf16* __restrict__ C, int M, int N, int K)
{
    __shared__ short lds[2][4][128 * 64];   // [buf][A0/A1/BG/BU] = 128 KiB

    const int tid = threadIdx.x;
    const int wid = tid >> 6, lane = tid & 63;
    const int wm = wid >> 1, wn = wid & 1;
    const int l16 = lane & 15, hk = lane >> 4;

    const int nwg = gridDim.x * gridDim.y;
    const int orig = blockIdx.y * gridDim.x + blockIdx.x;
    const int q = nwg >> 3, r8 = nwg & 7;
    const int xcd = orig & 7, lid = orig >> 3;
    const int wg = (xcd < r8 ? xcd * (q + 1) : r8 * (q + 1) + (xcd - r8) * q) + lid;
    const int bm = (wg % gridDim.y) * 256;
    const int bn = (wg / gridDim.y) * 128;

    f32x4 ag[4][4] = {}, au[4][4] = {};
    const int nt = K >> 6;

    auto stage_half = [&](const bf16* gbase, short* lbase) {
        #pragma unroll
        for (int i = 0; i < 2; ++i) {
            const int ch = i * 512 + tid;
            const int row = ch >> 3, pc = ch & 7;
            const int gc = pc ^ (row & 7);
            const char* src = (const char*)(gbase + (size_t)row * K + gc * 8);
            char* dst = (char*)lbase + (i * 512 + wid * 64) * 16;
            gload16(src, dst);
        }
    };

    stage_half(A + (size_t)bm * K,          &lds[0][0][0]);
    stage_half(A + (size_t)(bm + 128) * K,  &lds[0][1][0]);
    stage_half(BG + (size_t)bn * K,         &lds[0][2][0]);
    stage_half(BU + (size_t)bn * K,         &lds[0][3][0]);
    asm volatile("s_waitcnt vmcnt(0)" ::: "memory");
    __builtin_amdgcn_s_barrier();

    for (int t = 0; t < nt; ++t) {
        const int c = t & 1;
        const short* Ah = &lds[c][wm >> 1][0];
        const short* Gs = &lds[c][2][0];
        const short* Us = &lds[c][3][0];
        const int arr = (wm & 1) * 64;
        const int brr = wn * 64;
        const int k1 = (t + 1) << 6;

        short8_t gfr[4][2], ufr[4][2], afr[4][2];

        #pragma unroll
        for (int nf = 0; nf < 4; ++nf)
            #pragma unroll
            for (int ks = 0; ks < 2; ++ks) {
                gfr[nf][ks] = ldsfrag(Gs, brr + nf * 16 + l16, ks * 4 + hk);
                ufr[nf][ks] = ldsfrag(Us, brr + nf * 16 + l16, ks * 4 + hk);
            }
        #pragma unroll
        for (int mi = 0; mi < 4; ++mi)
            #pragma unroll
            for (int ks = 0; ks < 2; ++ks)
                afr[mi][ks] = ldsfrag(Ah, arr + mi * 16 + l16, ks * 4 + hk);
        if (t + 1 < nt) {
            stage_half(A + (size_t)bm * K + k1,         &lds[c ^ 1][0][0]);
            stage_half(A + (size_t)(bm + 128) * K + k1, &lds[c ^ 1][1][0]);
            stage_half(BG + (size_t)bn * K + k1,        &lds[c ^ 1][2][0]);
            stage_half(BU + (size_t)bn * K + k1,        &lds[c ^ 1][3][0]);
        }
        __builtin_amdgcn_s_setprio(1);
        #pragma unroll
        for (int mi = 0; mi < 4; ++mi)
            #pragma unroll
            for (int nf = 0; nf < 4; ++nf)
                #pragma unroll
                for (int ks = 0; ks < 2; ++ks) {
                    ag[mi][nf] = __builtin_amdgcn_mfma_f32_16x16x32_bf16(
                        afr[mi][ks], gfr[nf][ks], ag[mi][nf], 0, 0, 0);
                    au[mi][nf] = __builtin_amdgcn_mfma_f32_16x16x32_bf16(
                        afr[mi][ks], ufr[nf][ks], au[mi][nf], 0, 0, 0);
                }
        __builtin_amdgcn_s_setprio(0);

        asm volatile("s_waitcnt vmcnt(0)" ::: "memory");
        __builtin_amdgcn_s_barrier();
    }

    const int r0 = bm + wm * 64 + (lane >> 4) * 4;
    const int c0 = bn + wn * 64 + l16;
    #pragma unroll
    for (int mf = 0; mf < 4; ++mf)
        #pragma unroll
        for (int nf = 0; nf < 4; ++nf)
            #pragma unroll
            for (int r = 0; r < 4; ++r) {
                const float gg = ag[mf][nf][r];
                const float uu = au[mf][nf][r];
                const float v = gg / (1.f + __expf(-gg)) * uu;
                C[(size_t)(r0 + mf * 16 + r) * N + c0 + nf * 16] = __float2bfloat16(v);
            }
}

// ---------------------------------------------------------------------------
// RoPE v2: q_pe in place; k_pe -> all 16 heads' Kh[...][128:192].
// ---------------------------------------------------------------------------
__global__ __launch_bounds__(256) void rope_kernel(
    bf16* __restrict__ q, const float* __restrict__ ckv,
    bf16* __restrict__ Kh, const int* __restrict__ pos_ids,
    const float* __restrict__ sinT, const float* __restrict__ cosT)
{
    const int wid = blockIdx.x * 4 + (threadIdx.x >> 6);
    const int lane = threadIdx.x & 63;
    const int NQ = BS_ * NH_;

    int bs;
    float x;
    bf16* bptr = nullptr;
    if (wid < NQ) {
        bs = wid >> 4;
        bptr = q + (size_t)wid * QHD_ + NOPE_;
        x = __bfloat162float(bptr[lane]);
    } else {
        bs = wid - NQ;
        x = ckv[(size_t)bs * CKVP_ + KVL_ + lane];
    }
    const int pos = pos_ids[bs];
    const float c  = cosT[pos * ROPE_ + lane];
    const float sn = sinT[pos * ROPE_ + lane];
    const int j = lane & 31;
    const float x0 = __shfl(x, 2 * j);
    const float x1 = __shfl(x, 2 * j + 1);
    const float res = (lane < 32) ? fmaf(x0, c, -x1 * sn) : fmaf(x1, c, x0 * sn);
    if (bptr) {
        bptr[lane] = __float2bfloat16(res);
    } else {
        const int bb = bs >> 11, s = bs & 2047;
        const bf16 rv = __float2bfloat16(res);
        #pragma unroll
        for (int hh = 0; hh < NH_; ++hh)
            Kh[((size_t)(bb * NH_ + hh) * S_ + s) * QHD_ + NOPE_ + lane] = rv;
    }
}

// ---------------------------------------------------------------------------
// MFMA flash attention v5 (R15, proven) — double-buffered K/V LDS, one
// barrier per tile, launch_bounds(512,2).
// ---------------------------------------------------------------------------
__global__ __launch_bounds__(512, 2) void attn_mfma(
    const bf16* __restrict__ Qp, const bf16* __restrict__ Kh,
    const bf16* __restrict__ Vt, bf16* __restrict__ outp)
{
    __shared__ __align__(16) short Ks[2][64][192];
    __shared__ __align__(16) short Vs[2][128][64];
    __shared__ __align__(16) short Ps[8][16][64];

    const int tid = threadIdx.x;
    const int wid = tid >> 6, lane = tid & 63;
    const int l16 = lane & 15;
    const int hk  = lane >> 4;
    const int lk  = hk << 3;
    const int pr  = hk << 2;
    const int lx  = l16 & 7;

    const int bid = blockIdx.x;
    const int orig = (bid & 7) * 64 + (bid >> 3);
    const int j  = orig & 15;
    const int gh = orig >> 4;
    const int h = gh & 15, b = gh >> 4;

    const int setB = wid >> 2;
    const int qblk = setB ? (31 - j) : j;
    const int qw = qblk * 64 + (wid & 3) * 16;
    const int myNt = qblk + 1;
    const int ntStage = 32 - j;

    short8_t qf[6];
    const bf16* qbase = Qp + (((size_t)b * S_ + qw + l16) * NH_ + h) * QHD_;
    #pragma unroll
    for (int kk = 0; kk < 6; ++kk)
        qf[kk] = *(const short8_t*)(qbase + kk * 32 + lk);

    const bf16* Khb = Kh + (size_t)(b * NH_ + h) * S_ * QHD_;
    const bf16* Vtb = Vt + (size_t)(b * NH_ + h) * VHD_ * S_;

    f32x4 o[8] = {};
    float mr[4] = {-3.0e38f, -3.0e38f, -3.0e38f, -3.0e38f};
    float lr[4] = {0.f, 0.f, 0.f, 0.f};
    const float scale = 0.07216878364870323f;

    const int krow = tid >> 3, kc0 = (tid & 7) * 3;
    const int vrow = tid >> 2, vc0 = (tid & 3) * 2;

    short8_t kreg[3], vreg[2];
    auto load_tile = [&](int kt) {
        const short* ksrc = (const short*)(Khb + ((size_t)(kt * 64 + krow)) * QHD_);
        kreg[0] = *(const short8_t*)(ksrc + (kc0 + 0) * 8);
        kreg[1] = *(const short8_t*)(ksrc + (kc0 + 1) * 8);
        kreg[2] = *(const short8_t*)(ksrc + (kc0 + 2) * 8);
        const short* vsrc = (const short*)(Vtb + (size_t)vrow * S_ + kt * 64);
        vreg[0] = *(const short8_t*)(vsrc + (vc0 + 0) * 8);
        vreg[1] = *(const short8_t*)(vsrc + (vc0 + 1) * 8);
    };
    auto write_tile = [&](int buf) {
        const int kx = krow & 7, vx = vrow & 7;
        *(short8_t*)&Ks[buf][krow][((kc0 + 0) ^ kx) << 3] = kreg[0];
        *(short8_t*)&Ks[buf][krow][((kc0 + 1) ^ kx) << 3] = kreg[1];
        *(short8_t*)&Ks[buf][krow][((kc0 + 2) ^ kx) << 3] = kreg[2];
        *(short8_t*)&Vs[buf][vrow][((vc0 + 0) ^ vx) << 3] = vreg[0];
        *(short8_t*)&Vs[buf][vrow][((vc0 + 1) ^ vx) << 3] = vreg[1];
    };

    load_tile(0);
    write_tile(0);
    __syncthreads();

    for (int t = 0; t < ntStage; ++t) {
        const int cb = t & 1;
        if (t + 1 < ntStage) load_tile(t + 1);
        if (t < myNt) {
            const int k0 = t << 6;
            f32x4 s[4] = {};
            #pragma unroll
            for (int kk = 0; kk < 6; ++kk) {
                #pragma unroll
                for (int n = 0; n < 4; ++n) {
                    short8_t kf = *(const short8_t*)&Ks[cb][n * 16 + l16][((kk * 4 + hk) ^ lx) << 3];
                    s[n] = __builtin_amdgcn_mfma_f32_16x16x32_bf16(qf[kk], kf, s[n], 0, 0, 0);
                }
            }
            if (t == myNt - 1) {
                #pragma unroll
                for (int n = 0; n < 4; ++n) {
                    const int kg = k0 + n * 16 + l16;
                    #pragma unroll
                    for (int r = 0; r < 4; ++r) {
                        if (kg > qw + pr + r) s[n][r] = -3.0e38f;
                    }
                }
            }
            #pragma unroll
            for (int r = 0; r < 4; ++r) {
                float rm = fmaxf(fmaxf(s[0][r], s[1][r]), fmaxf(s[2][r], s[3][r]));
                rm = fmaxf(rm, __shfl_xor(rm, 1));
                rm = fmaxf(rm, __shfl_xor(rm, 2));
                rm = fmaxf(rm, __shfl_xor(rm, 4));
                rm = fmaxf(rm, __shfl_xor(rm, 8));
                const float mnew = fmaxf(mr[r], rm);
                const float corr = __expf((mr[r] - mnew) * scale);
                mr[r] = mnew;
                float rs = 0.f;
                #pragma unroll
                for (int n = 0; n < 4; ++n) {
                    const float p = __expf((s[n][r] - mnew) * scale);
                    s[n][r] = p;
                    rs += p;
                }
                rs += __shfl_xor(rs, 1);
                rs += __shfl_xor(rs, 2);
                rs += __shfl_xor(rs, 4);
                rs += __shfl_xor(rs, 8);
                lr[r] = lr[r] * corr + rs;
                #pragma unroll
                for (int n = 0; n < 8; ++n) o[n][r] *= corr;
            }
            #pragma unroll
            for (int n = 0; n < 4; ++n) {
                #pragma unroll
                for (int r = 0; r < 4; ++r) {
                    union { bf16 hh; short u; } cv;
                    cv.hh = __float2bfloat16(s[n][r]);
                    const int row = pr + r;
                    const int col = (((n * 2 + (l16 >> 3)) ^ (row & 7)) << 3) + (l16 & 7);
                    Ps[wid][row][col] = cv.u;
                }
            }
            #pragma unroll
            for (int kk2 = 0; kk2 < 2; ++kk2) {
                short8_t pf = *(const short8_t*)&Ps[wid][l16][((kk2 * 4 + hk) ^ lx) << 3];
                #pragma unroll
                for (int n = 0; n < 8; ++n) {
                    short8_t vf = *(const short8_t*)&Vs[cb][n * 16 + l16][((kk2 * 4 + hk) ^ lx) << 3];
                    o[n] = __builtin_amdgcn_mfma_f32_16x16x32_bf16(pf, vf, o[n], 0, 0, 0);
                }
            }
        }
        if (t + 1 < ntStage) write_tile((t + 1) & 1);
        __syncthreads();
    }

    float inv[4];
    #pragma unroll
    for (int r = 0; r < 4; ++r) inv[r] = 1.f / lr[r];
    bf16* ob = outp + (((size_t)b * S_ + qw + pr) * NH_ + h) * VHD_;
    #pragma unroll
    for (int r = 0; r < 4; ++r)
        #pragma unroll
        for (int n = 0; n < 8; ++n)
            ob[(size_t)r * (NH_ * VHD_) + n * 16 + l16] = __float2bfloat16(o[n][r] * inv[r]);
}

// ---------------------------------------------------------------------------
// Launch
// ---------------------------------------------------------------------------
extern "C" void kernel_launch(void* const* d_in, const int* in_sizes, int n_in,
                              void* d_out, int out_size, void* d_ws, size_t ws_size,
                              hipStream_t stream)
{
    const float* hidden  = (const float*)d_in[0];
    const float* ln1_w   = (const float*)d_in[1];
    const float* q_a_k   = (const float*)d_in[2];
    const float* q_a_ln  = (const float*)d_in[3];
    const float* q_b_k   = (const float*)d_in[4];
    const float* kv_a_k  = (const float*)d_in[5];
    const float* kv_a_ln = (const float*)d_in[6];
    const float* kv_b_k  = (const float*)d_in[7];
    const float* o_k     = (const float*)d_in[8];
    const float* ln2_w   = (const float*)d_in[9];
    const float* gate_k  = (const float*)d_in[10];
    const float* up_k    = (const float*)d_in[11];
    const float* down_k  = (const float*)d_in[12];
    const float* sinT    = (const float*)d_in[13];
    const float* cosT    = (const float*)d_in[14];
    const int*   pos     = (const int*)d_in[15];
    float* out = (float*)d_out;
    char* ws = (char*)d_ws;

    // ---- Phase-1 workspace layout ----
    bf16* qaT   = (bf16*)(ws + 0);            // [1536][2048]  6,291,456
    bf16* qbT   = (bf16*)(ws + 6291456);      // [3072][1536]  9,437,184
    bf16* kvaT  = (bf16*)(ws + 15728640);     // [640][2048]   2,621,440
    bf16* kvbT  = (bf16*)(ws + 18350080);     // [4096][512]   4,194,304
    bf16* oT    = (bf16*)(ws + 22544384);     // [2048][2048]  8,388,608
    bf16* Xb    = (bf16*)(ws + 30932992);     // [4096][2048] 16,777,216
    bf16* QAb   = (bf16*)(ws + 47710208);     // [4096][1536] 12,582,912
    bf16* CKVNb = (bf16*)(ws + 60293120);     // [4096][512]   4,194,304
    bf16* Qb    = (bf16*)(ws + 64487424);     // [4096][3072] 25,165,824
    float* CKV  = (float*)(ws + 89653248);    // [4096][640]  10,485,760
    float* KV   = (float*)(ws + 100139008);   // [4096][4096] 67,108,864 (dead; kept for layout)
    bf16* ATTNb = (bf16*)(ws + 167247872);    // [4096][2048] 16,777,216
    bf16* Vt    = (bf16*)(ws + 0);            // overlays dead qaT/qbT/kvaT
    bf16* Kh    = (bf16*)(ws + 30932992);     // overlays dead Xb+QAb(part)
    // ---- Phase-2 layout ----
    bf16* gateT = (bf16*)(ws + 0);            // [8192][2048] 33,554,432
    bf16* upT   = (bf16*)(ws + 33554432);     // [8192][2048] 33,554,432
    bf16* downT = (bf16*)(ws + 67108864);     // [2048][8192] 33,554,432
    bf16* X2b   = (bf16*)(ws + 100663296);    // [4096][2048] 16,777,216
    bf16* MLPb  = (bf16*)(ws + 117440512);    // [4096][8192] 67,108,864

    const dim3 tb(32, 8);

    // 0. weight transposes (attention-phase weights); grid (Npad/32, K/64)
    transp_bf16<<<dim3(1536 / 32, 2048 / 64), tb, 0, stream>>>(q_a_k, qaT, 2048, 1536, 1536);
    transp_bf16<<<dim3(3072 / 32, 1536 / 64), tb, 0, stream>>>(q_b_k, qbT, 1536, 3072, 3072);
    transp_bf16<<<dim3(640 / 32, 2048 / 64), tb, 0, stream>>>(kv_a_k, kvaT, 2048, 576, 640);
    transp_bf16<<<dim3(4096 / 32, 512 / 64), tb, 0, stream>>>(kv_b_k, kvbT, 512, 4096, 4096);
    transp_bf16<<<dim3(2048 / 32, 2048 / 64), tb, 0, stream>>>(o_k, oT, 2048, 2048, 2048);

    // 1. Xb = rmsnorm(hidden)
    rmsnorm2<float, bf16><<<BS_, 256, 0, stream>>>(hidden, ln1_w, Xb, H_, H_, H_);
    // 2. QAb = Xb @ qaT   (n128 v4, grid 12x16)
    gemm256n128<0, bf16><<<dim3(QL_ / 128, BS_ / 256), 512, 0, stream>>>(
        Xb, qaT, nullptr, nullptr, QAb, BS_, QL_, H_);
    // 3. QAb = rmsnorm(QAb) in place
    rmsnorm2<bf16, bf16><<<BS_, 256, 0, stream>>>(QAb, q_a_ln, QAb, QL_, QL_, QL_);
    // 4. Qb = QAb @ qbT   (n128 v4, grid 24x16)
    gemm256n128<0, bf16><<<dim3((NH_ * QHD_) / 128, BS_ / 256), 512, 0, stream>>>(
        QAb, qbT, nullptr, nullptr, Qb, BS_, NH_ * QHD_, QL_);
    // 5. CKV = Xb @ kvaT (fp32, padded width 640; n128 v4, grid 5x16)
    gemm256n128<0, float><<<dim3(CKVP_ / 128, BS_ / 256), 512, 0, stream>>>(
        Xb, kvaT, nullptr, nullptr, CKV, BS_, CKVP_, H_);
    // 6. CKVNb = rmsnorm(CKV[:, :512])
    rmsnorm2<float, bf16><<<BS_, 256, 0, stream>>>(CKV, kv_a_ln, CKVNb, KVL_, CKVP_, KVL_);
    // 7. Kh/Vt = CKVNb @ kvbT (MODE 3: k_nope -> Kh; v -> Vt transposed direct)
    gemm256<3, float><<<dim3((NH_ * KVW_) / 256, BS_ / 256), 512, 0, stream>>>(
        CKVNb, kvbT, nullptr, nullptr, KV, Kh, Vt, BS_, NH_ * KVW_, KVL_);
    // 8. RoPE: q_pe in place; k_pe -> Kh[*][128:192] for all heads
    rope_kernel<<<(BS_ * NH_ + BS_) / 4, 256, 0, stream>>>(Qb, CKV, Kh, pos, sinT, cosT);
    // 9. MFMA flash attention v5 -> ATTNb
    attn_mfma<<<dim3(512), 512, 0, stream>>>(Qb, Kh, Vt, ATTNb);
    // 10. d_out = ATTNb @ oT + hidden (fp32, n128 v4, grid 16x16)
    gemm256n128<1, float><<<dim3(H_ / 128, BS_ / 256), 512, 0, stream>>>(
        ATTNb, oT, hidden, nullptr, out, BS_, H_, NH_ * VHD_);

    // 11. MLP-phase weight transposes
    transp_bf16<<<dim3(8192 / 32, 2048 / 64), tb, 0, stream>>>(gate_k, gateT, 2048, 8192, 8192);
    transp_bf16<<<dim3(8192 / 32, 2048 / 64), tb, 0, stream>>>(up_k, upT, 2048, 8192, 8192);
    transp_bf16<<<dim3(2048 / 32, 8192 / 64), tb, 0, stream>>>(down_k, downT, 8192, 2048, 2048);

    // 12. X2b = rmsnorm(d_out)
    rmsnorm2<float, bf16><<<BS_, 256, 0, stream>>>(out, ln2_w, X2b, H_, H_, H_);
    // 13. MLPb = silu(X2b @ gateT) * (X2b @ upT)  — fused dual GEMM (v4)
    gemm256dual<<<dim3(FF_ / 128, BS_ / 256), 512, 0, stream>>>(
        X2b, gateT, upT, MLPb, BS_, FF_, H_);
    // 14. d_out = MLPb @ downT + d_out (n128 v4, grid 16x16)
    gemm256n128<1, float><<<dim3(H_ / 128, BS_ / 256), 512, 0, stream>>>(
        MLPb, downT, out, nullptr, out, BS_, H_, FF_);
}